// Round 1
// baseline (8453.963 us; speedup 1.0000x reference)
//
#include <hip/hip_runtime.h>
#include <float.h>
#include <math.h>

// Problem constants
#define BB 16
#define LL 400
#define TT 40
#define HH 256
#define EE 256
#define VOCAB 50000
#define TILE_V 64
#define NTILE 782   // ceil(50000/64)

struct Ctx {
  // inputs
  const float *enc_states, *enc_h, *enc_c, *embed;
  const float *Wih, *Whh, *bih, *bhh;
  const float *Wh_w, *Wh_b, *Ws_w, *Ws_b;
  const float *wc_w, *wc_b, *v_w, *v_b;
  const float *wh_w, *wh_b, *ws_w, *ws_b, *wx_w, *wx_b;
  const float *V_w, *V_b;
  const int *dec_input, *targets, *article_inds;
  const unsigned char *enc_mask;
  // workspace
  float *Gx;        // [T,B,1024] x-part of LSTM gates (+biases)
  float *hs;        // [T,B,256]
  float *dec_proj;  // [T,B,512]
  float *enc_proj;  // [B,L,512]
  float *WihT, *WhhT, *WsT, *WhT;  // transposed weights
  float *coverage;  // [B,L]
  float *scores;    // [B,L]
  float *hc;        // [B,768] = concat(h_t, context)
  float *pairs_m, *pairs_s;  // [B,NTILE] online-softmax tile pairs
  float *px, *hws;  // [T*B] e.wx, h.ws dots
  float *pgen, *attn_match, *logit_g, *lm_sum, *covl_sum; // [B]
  float *h_buf;     // [2][B*256] double-buffered h state for LSTM
  unsigned *bar;    // barrier counter
  float *out;       // [B]
};

__device__ __forceinline__ float sigf(float x) { return 1.f / (1.f + expf(-x)); }

// ---------------- init: zero accumulators ----------------
__global__ void k_init(Ctx c) {
  int i = blockIdx.x * 256 + threadIdx.x;
  if (i < BB * LL) c.coverage[i] = 0.f;
  if (i < BB) { c.lm_sum[i] = 0.f; c.covl_sum[i] = 0.f; }
  if (i == 0) *c.bar = 0u;
}

// ---------------- tiled transpose: in[R][C] -> out[C][R] ----------------
__global__ void k_transpose(const float* __restrict__ in, float* __restrict__ out, int R, int C) {
  __shared__ float tile[32][33];
  int bx = blockIdx.x * 32, by = blockIdx.y * 32;
  int tx = threadIdx.x, ty = threadIdx.y;
  for (int i = ty; i < 32; i += 8) tile[i][tx] = in[(by + i) * C + bx + tx];
  __syncthreads();
  for (int i = ty; i < 32; i += 8) out[(bx + i) * R + by + tx] = tile[tx][i];
}

// ---------------- Gx = embed[dec_input] @ Wih^T + bih + bhh ; px = e.wx ----------------
__global__ void k_gx(Ctx c) {
  int tb = blockIdx.x;            // t*16+b
  int t = tb >> 4, b = tb & 15;
  int tid = threadIdx.x;          // 256
  __shared__ float x[EE];
  __shared__ float red[256];
  int tok = c.dec_input[b * TT + t];
  x[tid] = c.embed[(size_t)tok * EE + tid];
  __syncthreads();
  const float4* WT4 = (const float4*)c.WihT;
  float4 acc = ((const float4*)c.bih)[tid];
  float4 b2 = ((const float4*)c.bhh)[tid];
  acc.x += b2.x; acc.y += b2.y; acc.z += b2.z; acc.w += b2.w;
#pragma unroll 4
  for (int k = 0; k < EE; ++k) {
    float xv = x[k];
    float4 w = WT4[k * 256 + tid];
    acc.x += xv * w.x; acc.y += xv * w.y; acc.z += xv * w.z; acc.w += xv * w.w;
  }
  ((float4*)c.Gx)[tb * 256 + tid] = acc;
  red[tid] = x[tid] * c.wx_w[tid];
  __syncthreads();
  for (int s = 128; s > 0; s >>= 1) { if (tid < s) red[tid] += red[tid + s]; __syncthreads(); }
  if (tid == 0) c.px[tb] = red[0];
}

// ---------------- persistent LSTM: 32 WGs, Whh slice LDS-resident ----------------
// WG iw owns gate cols {q*256 + iw*8 + jj : q<4, jj<8} and h elements j in [iw*8, iw*8+8)
__global__ void __launch_bounds__(256) k_lstm(Ctx c) {
  __shared__ float Wl[256 * 32];    // [k][32 cols]
  __shared__ float hl[16 * 260];    // padded h state, all batches
  __shared__ float gs[16 * 36];     // gate slice per batch
  int iw = blockIdx.x, tid = threadIdx.x;
  for (int idx = tid; idx < 8192; idx += 256) {
    int k = idx >> 5, col = idx & 31, q = col >> 3, jj = col & 7;
    Wl[idx] = c.WhhT[k * 1024 + q * 256 + iw * 8 + jj];
  }
  for (int idx = tid; idx < 4096; idx += 256) {
    int b0 = idx >> 8, k0 = idx & 255;
    hl[b0 * 260 + k0] = c.enc_h[idx];
  }
  int b = tid >> 4, cg = tid & 15;          // compute mapping: cols 2cg, 2cg+1
  int bu = tid >> 3, ju = tid & 7;          // update mapping (tid < 128)
  float creg = 0.f;
  if (tid < 128) creg = c.enc_c[bu * 256 + iw * 8 + ju];
  __syncthreads();
  const float2* Wl2 = (const float2*)Wl;
  const float2* Gx2 = (const float2*)c.Gx;
  for (int t = 0; t < TT; ++t) {
    int q = cg >> 2;
    float2 acc = Gx2[(t * 16 + b) * 512 + q * 128 + iw * 4 + (cg & 3)];
#pragma unroll 4
    for (int k = 0; k < 256; ++k) {
      float hv = hl[b * 260 + k];
      float2 w = Wl2[k * 16 + cg];
      acc.x += hv * w.x; acc.y += hv * w.y;
    }
    ((float2*)(gs + b * 36 + 2 * cg))[0] = acc;
    __syncthreads();
    if (tid < 128) {
      float ig = gs[bu * 36 + ju];
      float fg = gs[bu * 36 + 8 + ju];
      float gg = gs[bu * 36 + 16 + ju];
      float og = gs[bu * 36 + 24 + ju];
      creg = sigf(fg) * creg + sigf(ig) * tanhf(gg);
      float hv = sigf(og) * tanhf(creg);
      int j = iw * 8 + ju;
      c.h_buf[((t + 1) & 1) * 4096 + bu * 256 + j] = hv;
      c.hs[(t * 16 + bu) * 256 + j] = hv;
    }
    // device barrier (monotonic counter; 32 WGs co-resident)
    __threadfence();
    __syncthreads();
    if (tid == 0) {
      __hip_atomic_fetch_add(c.bar, 1u, __ATOMIC_ACQ_REL, __HIP_MEMORY_SCOPE_AGENT);
      while (__hip_atomic_load(c.bar, __ATOMIC_ACQUIRE, __HIP_MEMORY_SCOPE_AGENT) < (unsigned)(32 * (t + 1)))
        __builtin_amdgcn_s_sleep(2);
      __threadfence();
    }
    __syncthreads();
    if (t < TT - 1) {
      int par = (t + 1) & 1;
      for (int idx = tid; idx < 4096; idx += 256) {
        int b0 = idx >> 8, k0 = idx & 255;
        hl[b0 * 260 + k0] = c.h_buf[par * 4096 + idx];
      }
      __syncthreads();
    }
  }
}

// ---------------- dec_proj = hs @ Ws^T + Ws_b ; hws = h.ws ----------------
__global__ void k_decproj(Ctx c) {
  int tb = blockIdx.x, tid = threadIdx.x;  // block 512
  __shared__ float h[256];
  __shared__ float red[256];
  if (tid < 256) h[tid] = c.hs[tb * 256 + tid];
  __syncthreads();
  float acc = c.Ws_b[tid];
#pragma unroll 4
  for (int k = 0; k < 256; ++k) acc += h[k] * c.WsT[k * 512 + tid];
  c.dec_proj[tb * 512 + tid] = acc;
  if (tid < 256) red[tid] = h[tid] * c.ws_w[tid];
  __syncthreads();
  for (int s = 128; s > 0; s >>= 1) { if (tid < 256 && tid < s) red[tid] += red[tid + s]; __syncthreads(); }
  if (tid == 0) c.hws[tb] = red[0];
}

// ---------------- enc_proj = enc_states @ Wh^T + Wh_b ----------------
__global__ void k_encproj(Ctx c) {
  int b = blockIdx.x / 100, lt = (blockIdx.x % 100) * 4, tid = threadIdx.x; // block 512
  __shared__ float es[4][512];
  for (int i = 0; i < 4; ++i) es[i][tid] = c.enc_states[(size_t)(b * LL + lt + i) * 512 + tid];
  __syncthreads();
  float bias = c.Wh_b[tid];
  float a0 = bias, a1 = bias, a2 = bias, a3 = bias;
#pragma unroll 4
  for (int k = 0; k < 512; ++k) {
    float w = c.WhT[k * 512 + tid];
    a0 += es[0][k] * w; a1 += es[1][k] * w; a2 += es[2][k] * w; a3 += es[3][k] * w;
  }
  c.enc_proj[(size_t)(b * LL + lt + 0) * 512 + tid] = a0;
  c.enc_proj[(size_t)(b * LL + lt + 1) * 512 + tid] = a1;
  c.enc_proj[(size_t)(b * LL + lt + 2) * 512 + tid] = a2;
  c.enc_proj[(size_t)(b * LL + lt + 3) * 512 + tid] = a3;
}

// ---------------- S1: attention scores (one wave per (b,l)) ----------------
__global__ void k_scores(Ctx c, int t) {
  int wv = blockIdx.x * 4 + (threadIdx.x >> 6);
  int lane = threadIdx.x & 63;
  int b = wv / 400, l = wv % 400;
  float cov = c.coverage[b * LL + l];
  const float* ep = c.enc_proj + (size_t)(b * LL + l) * 512;
  const float* dp = c.dec_proj + (size_t)(t * 16 + b) * 512;
  float acc = 0.f;
#pragma unroll
  for (int i = 0; i < 8; ++i) {
    int j = lane + 64 * i;
    float f = ep[j] + dp[j] + cov * c.wc_w[j] + c.wc_b[j];
    acc += tanhf(f) * c.v_w[j];
  }
  for (int off = 1; off < 64; off <<= 1) acc += __shfl_xor(acc, off, 64);
  if (lane == 0) {
    float s = acc + c.v_b[0];
    if (c.enc_mask[b * LL + l]) s = -1e30f;
    c.scores[b * LL + l] = s;
  }
}

// ---------------- S2: loss(t-1) + softmax + context + pgen + coverage ----------------
__global__ void k_step(Ctx c, int t) {
  int b = blockIdx.x, tid = threadIdx.x; // block 512
  __shared__ float red[512];
  __shared__ float attn_s[400];
  // Phase A: finish loss for step t-1 using tile pairs from k_vocab(t-1)
  if (t > 0) {
    float m = -FLT_MAX;
    for (int i = tid; i < NTILE; i += 512) m = fmaxf(m, c.pairs_m[b * NTILE + i]);
    red[tid] = m; __syncthreads();
    for (int s = 256; s > 0; s >>= 1) { if (tid < s) red[tid] = fmaxf(red[tid], red[tid + s]); __syncthreads(); }
    float M = red[0]; __syncthreads();
    float z = 0.f;
    for (int i = tid; i < NTILE; i += 512) z += c.pairs_s[b * NTILE + i] * expf(c.pairs_m[b * NTILE + i] - M);
    red[tid] = z; __syncthreads();
    for (int s = 256; s > 0; s >>= 1) { if (tid < s) red[tid] += red[tid + s]; __syncthreads(); }
    if (tid == 0) {
      int tgt = c.targets[b * TT + (t - 1)];
      if (tgt != 0) {
        float p = expf(c.logit_g[b] - M) / red[0];
        float pg = c.pgen[b];
        float o = pg * p + (1.f - pg) * c.attn_match[b];
        c.lm_sum[b] += -logf(o);
      }
    }
    __syncthreads();
  }
  // Phase B: softmax over L
  float sc = (tid < 400) ? c.scores[b * LL + tid] : -FLT_MAX;
  red[tid] = sc; __syncthreads();
  for (int s = 256; s > 0; s >>= 1) { if (tid < s) red[tid] = fmaxf(red[tid], red[tid + s]); __syncthreads(); }
  float M2 = red[0]; __syncthreads();
  float ex = (tid < 400) ? expf(sc - M2) : 0.f;
  red[tid] = ex; __syncthreads();
  for (int s = 256; s > 0; s >>= 1) { if (tid < s) red[tid] += red[tid + s]; __syncthreads(); }
  float S = red[0]; __syncthreads();
  float a = ex / S;
  if (tid < 400) attn_s[tid] = a;
  // coverage update + covl + scatter-match for target index
  int tgt_t = c.targets[b * TT + t];
  int gidx = (tgt_t != 0) ? tgt_t - 1 : 0;
  float cvp = 0.f, mct = 0.f;
  if (tid < 400) {
    float nc = c.coverage[b * LL + tid] + a;
    c.coverage[b * LL + tid] = nc;
    cvp = fminf(nc, a);
    int idx = c.enc_mask[b * LL + tid] ? 0 : (c.article_inds[b * LL + tid] - 1);
    mct = (idx == gidx) ? a : 0.f;
  }
  red[tid] = cvp; __syncthreads();
  for (int s = 256; s > 0; s >>= 1) { if (tid < s) red[tid] += red[tid + s]; __syncthreads(); }
  if (tid == 0) c.covl_sum[b] += red[0];
  __syncthreads();
  red[tid] = mct; __syncthreads();
  for (int s = 256; s > 0; s >>= 1) { if (tid < s) red[tid] += red[tid + s]; __syncthreads(); }
  if (tid == 0) c.attn_match[b] = red[0];
  __syncthreads();
  // Phase C: context = attn @ enc_states ; build hc = [h_t, context]
  float ctx = 0.f;
#pragma unroll 4
  for (int l = 0; l < 400; ++l) ctx += attn_s[l] * c.enc_states[(size_t)(b * LL + l) * 512 + tid];
  c.hc[b * 768 + 256 + tid] = ctx;
  if (tid < 256) c.hc[b * 768 + tid] = c.hs[(t * 16 + b) * 256 + tid];
  // Phase D: p_gen
  red[tid] = ctx * c.wh_w[tid]; __syncthreads();
  for (int s = 256; s > 0; s >>= 1) { if (tid < s) red[tid] += red[tid + s]; __syncthreads(); }
  if (tid == 0) {
    float pg = red[0] + c.wh_b[0] + c.hws[t * 16 + b] + c.ws_b[0] + c.px[t * 16 + b] + c.wx_b[0];
    c.pgen[b] = sigf(pg);
  }
}

// ---------------- S3: vocab logits -> per-tile online softmax pairs ----------------
// lanes: b = lane>>2 (16 batches), jg = lane&3 (k-quarter); all batches share each V_w row read
__global__ void k_vocab(Ctx c, int t) {
  __shared__ float4 hc4[16 * 192];
  __shared__ float pm[4][16], ps[4][16];
  int tid = threadIdx.x;  // block 256
  const float4* hcg = (const float4*)c.hc;
  for (int idx = tid; idx < 3072; idx += 256) hc4[idx] = hcg[idx];
  __syncthreads();
  int wave = tid >> 6, lane = tid & 63;
  int jg = lane & 3, bb = lane >> 2;
  int tgt = c.targets[bb * TT + t];
  int gidx = (tgt != 0) ? tgt - 1 : 0;
  float mrun = -FLT_MAX, srun = 0.f;
  int v0 = blockIdx.x * TILE_V + wave * 16;
  const float4* VW = (const float4*)c.V_w;
  for (int it = 0; it < 16; ++it) {
    int v = v0 + it;
    if (v >= VOCAB) break;              // wave-uniform
    const float4* vr = VW + (size_t)v * 192;
    float4 acc4 = {0.f, 0.f, 0.f, 0.f};
#pragma unroll 4
    for (int i = 0; i < 48; ++i) {
      float4 w = vr[4 * i + jg];
      float4 h = hc4[bb * 192 + 4 * i + jg];
      acc4.x += w.x * h.x; acc4.y += w.y * h.y; acc4.z += w.z * h.z; acc4.w += w.w * h.w;
    }
    float acc = (acc4.x + acc4.y) + (acc4.z + acc4.w);
    acc += __shfl_xor(acc, 1, 64);
    acc += __shfl_xor(acc, 2, 64);
    if (jg == 0) {
      float lg = acc + c.V_b[v];
      if (v == gidx) c.logit_g[bb] = lg;
      if (lg > mrun) { srun = srun * expf(mrun - lg) + 1.f; mrun = lg; }
      else srun += expf(lg - mrun);
    }
  }
  if (jg == 0) { pm[wave][bb] = mrun; ps[wave][bb] = srun; }
  __syncthreads();
  if (tid < 16) {
    float M = fmaxf(fmaxf(pm[0][tid], pm[1][tid]), fmaxf(pm[2][tid], pm[3][tid]));
    float S = 0.f;
    for (int w2 = 0; w2 < 4; ++w2) S += ps[w2][tid] * expf(pm[w2][tid] - M);
    c.pairs_m[tid * NTILE + blockIdx.x] = M;
    c.pairs_s[tid * NTILE + blockIdx.x] = S;
  }
}

// ---------------- finalize: loss for t=39 + output ----------------
__global__ void k_final(Ctx c) {
  int b = blockIdx.x, tid = threadIdx.x; // block 512
  __shared__ float red[512];
  float m = -FLT_MAX;
  for (int i = tid; i < NTILE; i += 512) m = fmaxf(m, c.pairs_m[b * NTILE + i]);
  red[tid] = m; __syncthreads();
  for (int s = 256; s > 0; s >>= 1) { if (tid < s) red[tid] = fmaxf(red[tid], red[tid + s]); __syncthreads(); }
  float M = red[0]; __syncthreads();
  float z = 0.f;
  for (int i = tid; i < NTILE; i += 512) z += c.pairs_s[b * NTILE + i] * expf(c.pairs_m[b * NTILE + i] - M);
  red[tid] = z; __syncthreads();
  for (int s = 256; s > 0; s >>= 1) { if (tid < s) red[tid] += red[tid + s]; __syncthreads(); }
  float Z = red[0]; __syncthreads();
  float dl = (tid < TT && c.dec_input[b * TT + tid] > 0) ? 1.f : 0.f;
  red[tid] = dl; __syncthreads();
  for (int s = 256; s > 0; s >>= 1) { if (tid < s) red[tid] += red[tid + s]; __syncthreads(); }
  if (tid == 0) {
    float dlen = red[0];
    int tgt = c.targets[b * TT + 39];
    float lm39 = 0.f;
    if (tgt != 0) {
      float p = expf(c.logit_g[b] - M) / Z;
      float pg = c.pgen[b];
      lm39 = -logf(pg * p + (1.f - pg) * c.attn_match[b]);
    }
    c.out[b] = (c.lm_sum[b] + lm39) / dlen + c.covl_sum[b] / dlen;
  }
}

extern "C" void kernel_launch(void* const* d_in, const int* in_sizes, int n_in,
                              void* d_out, int out_size, void* d_ws, size_t ws_size,
                              hipStream_t stream) {
  Ctx c;
  c.enc_states = (const float*)d_in[0];
  c.enc_h      = (const float*)d_in[1];
  c.enc_c      = (const float*)d_in[2];
  c.embed      = (const float*)d_in[3];
  c.Wih        = (const float*)d_in[4];
  c.Whh        = (const float*)d_in[5];
  c.bih        = (const float*)d_in[6];
  c.bhh        = (const float*)d_in[7];
  c.Wh_w       = (const float*)d_in[8];
  c.Wh_b       = (const float*)d_in[9];
  c.Ws_w       = (const float*)d_in[10];
  c.Ws_b       = (const float*)d_in[11];
  c.wc_w       = (const float*)d_in[12];
  c.wc_b       = (const float*)d_in[13];
  c.v_w        = (const float*)d_in[14];
  c.v_b        = (const float*)d_in[15];
  c.wh_w       = (const float*)d_in[16];
  c.wh_b       = (const float*)d_in[17];
  c.ws_w       = (const float*)d_in[18];
  c.ws_b       = (const float*)d_in[19];
  c.wx_w       = (const float*)d_in[20];
  c.wx_b       = (const float*)d_in[21];
  c.V_w        = (const float*)d_in[22];
  c.V_b        = (const float*)d_in[23];
  c.dec_input  = (const int*)d_in[24];
  c.targets    = (const int*)d_in[25];
  c.article_inds = (const int*)d_in[26];
  c.enc_mask   = (const unsigned char*)d_in[27];

  // workspace carve-up (~20.6 MiB total; all chunks multiples of 16 floats)
  float* p = (float*)d_ws;
  c.Gx = p;        p += TT * BB * 1024;
  c.hs = p;        p += TT * BB * 256;
  c.dec_proj = p;  p += TT * BB * 512;
  c.enc_proj = p;  p += (size_t)BB * LL * 512;
  c.WihT = p;      p += 1024 * 256;
  c.WhhT = p;      p += 1024 * 256;
  c.WsT = p;       p += 512 * 256;
  c.WhT = p;       p += 512 * 512;
  c.coverage = p;  p += BB * LL;
  c.scores = p;    p += BB * LL;
  c.hc = p;        p += BB * 768;
  c.pairs_m = p;   p += BB * NTILE;
  c.pairs_s = p;   p += BB * NTILE;
  c.px = p;        p += TT * BB;
  c.hws = p;       p += TT * BB;
  c.pgen = p;        p += 16;
  c.attn_match = p;  p += 16;
  c.logit_g = p;     p += 16;
  c.lm_sum = p;      p += 16;
  c.covl_sum = p;    p += 16;
  c.h_buf = p;       p += 2 * BB * 256;
  c.bar = (unsigned*)p; p += 16;
  c.out = (float*)d_out;

  k_init<<<26, 256, 0, stream>>>(c);
  k_transpose<<<dim3(8, 32), dim3(32, 8), 0, stream>>>(c.Wih, c.WihT, 1024, 256);
  k_transpose<<<dim3(8, 32), dim3(32, 8), 0, stream>>>(c.Whh, c.WhhT, 1024, 256);
  k_transpose<<<dim3(8, 16), dim3(32, 8), 0, stream>>>(c.Ws_w, c.WsT, 512, 256);
  k_transpose<<<dim3(16, 16), dim3(32, 8), 0, stream>>>(c.Wh_w, c.WhT, 512, 512);
  k_gx<<<TT * BB, 256, 0, stream>>>(c);
  k_encproj<<<16 * 100, 512, 0, stream>>>(c);
  k_lstm<<<32, 256, 0, stream>>>(c);
  k_decproj<<<TT * BB, 512, 0, stream>>>(c);
  for (int t = 0; t < TT; ++t) {
    k_scores<<<1600, 256, 0, stream>>>(c, t);
    k_step<<<16, 512, 0, stream>>>(c, t);
    k_vocab<<<NTILE, 256, 0, stream>>>(c, t);
  }
  k_final<<<16, 512, 0, stream>>>(c);
}

// Round 2
// 3553.260 us; speedup vs baseline: 2.3792x; 2.3792x over previous
//
#include <hip/hip_runtime.h>
#include <float.h>
#include <math.h>

// Problem constants
#define BB 16
#define LL 400
#define TT 40
#define HH 256
#define EE 256
#define VOCAB 50000
#define NT 3128   // vocab tiles of 16 rows: ceil(50000/16) rounded to 782 blocks * 4 waves

typedef __attribute__((ext_vector_type(8))) short bf16x8;
typedef __attribute__((ext_vector_type(4))) float f32x4;
typedef __attribute__((ext_vector_type(8))) unsigned short ushort8;

struct Ctx {
  // inputs
  const float *enc_states, *enc_h, *enc_c, *embed;
  const float *Wih, *Whh, *bih, *bhh;
  const float *Wh_w, *Wh_b, *Ws_w, *Ws_b;
  const float *wc_w, *wc_b, *v_w, *v_b;
  const float *wh_w, *wh_b, *ws_w, *ws_b, *wx_w, *wx_b;
  const float *V_w, *V_b;
  const int *dec_input, *targets, *article_inds;
  const unsigned char *enc_mask;
  // workspace
  float *Gx;        // [T,B,1024] x-part of LSTM gates (+biases)
  float *hs;        // [T,B,256]
  float *dec_proj;  // [T,B,512]
  float *enc_proj;  // [B,L,512]
  float *WihT, *WhhT, *WsT, *WhT;  // transposed weights
  float *coverage;  // [B,L]
  float *scores;    // [B,L]
  unsigned short *hcb; // [96][16][8] bf16 chunked A-fragments of concat(h, ctx)
  float *pairs_m, *pairs_s;  // [B,NT] online-softmax tile pairs
  float *px, *hws;  // [T*B] e.wx, h.ws dots
  float *pgen, *attn_match, *logit_g, *lm_sum, *covl_sum; // [B]
  float *h_buf;     // [2][B*256] double-buffered h state for LSTM
  unsigned *bar;    // barrier counter
  unsigned short *Vb16;  // [50000][768] bf16 copy of V_w (optional)
  int use_bf16;
  float *out;       // [B]
};

__device__ __forceinline__ float sigf(float x) { return 1.f / (1.f + expf(-x)); }

__device__ __forceinline__ unsigned short f2bf(float x) {
  unsigned u = __builtin_bit_cast(unsigned, x);
  u = (u + 0x7FFFu + ((u >> 16) & 1u)) >> 16;
  return (unsigned short)u;
}

// ---------------- init: zero accumulators ----------------
__global__ void k_init(Ctx c) {
  int i = blockIdx.x * 256 + threadIdx.x;
  if (i < BB * LL) c.coverage[i] = 0.f;
  if (i < BB) { c.lm_sum[i] = 0.f; c.covl_sum[i] = 0.f; }
  if (i == 0) *c.bar = 0u;
}

// ---------------- V_w fp32 -> bf16 ----------------
__global__ void k_cvt(const float* __restrict__ src, unsigned short* __restrict__ dst, int ngroups) {
  int i = blockIdx.x * 256 + threadIdx.x;
  int stride = gridDim.x * 256;
  const float4* s4 = (const float4*)src;
  ushort8* d8 = (ushort8*)dst;
  for (; i < ngroups; i += stride) {
    float4 a = s4[2 * i], b = s4[2 * i + 1];
    ushort8 o;
    o[0] = f2bf(a.x); o[1] = f2bf(a.y); o[2] = f2bf(a.z); o[3] = f2bf(a.w);
    o[4] = f2bf(b.x); o[5] = f2bf(b.y); o[6] = f2bf(b.z); o[7] = f2bf(b.w);
    d8[i] = o;
  }
}

// ---------------- tiled transpose: in[R][C] -> out[C][R] ----------------
__global__ void k_transpose(const float* __restrict__ in, float* __restrict__ out, int R, int C) {
  __shared__ float tile[32][33];
  int bx = blockIdx.x * 32, by = blockIdx.y * 32;
  int tx = threadIdx.x, ty = threadIdx.y;
  for (int i = ty; i < 32; i += 8) tile[i][tx] = in[(by + i) * C + bx + tx];
  __syncthreads();
  for (int i = ty; i < 32; i += 8) out[(bx + i) * R + by + tx] = tile[tx][i];
}

// ---------------- Gx = embed[dec_input] @ Wih^T + bih + bhh ; px = e.wx ----------------
__global__ void k_gx(Ctx c) {
  int tb = blockIdx.x;            // t*16+b
  int t = tb >> 4, b = tb & 15;
  int tid = threadIdx.x;          // 256
  __shared__ float x[EE];
  __shared__ float red[256];
  int tok = c.dec_input[b * TT + t];
  x[tid] = c.embed[(size_t)tok * EE + tid];
  __syncthreads();
  const float4* WT4 = (const float4*)c.WihT;
  float4 acc = ((const float4*)c.bih)[tid];
  float4 b2 = ((const float4*)c.bhh)[tid];
  acc.x += b2.x; acc.y += b2.y; acc.z += b2.z; acc.w += b2.w;
#pragma unroll 4
  for (int k = 0; k < EE; ++k) {
    float xv = x[k];
    float4 w = WT4[k * 256 + tid];
    acc.x += xv * w.x; acc.y += xv * w.y; acc.z += xv * w.z; acc.w += xv * w.w;
  }
  ((float4*)c.Gx)[tb * 256 + tid] = acc;
  red[tid] = x[tid] * c.wx_w[tid];
  __syncthreads();
  for (int s = 128; s > 0; s >>= 1) { if (tid < s) red[tid] += red[tid + s]; __syncthreads(); }
  if (tid == 0) c.px[tb] = red[0];
}

// ---------------- persistent LSTM: 32 WGs, Whh slice LDS-resident ----------------
__global__ void __launch_bounds__(256) k_lstm(Ctx c) {
  __shared__ float Wl[256 * 32];    // [k][32 cols]
  __shared__ float hl[16 * 260];    // padded h state, all batches
  __shared__ float gs[16 * 36];     // gate slice per batch
  int iw = blockIdx.x, tid = threadIdx.x;
  for (int idx = tid; idx < 8192; idx += 256) {
    int k = idx >> 5, col = idx & 31, q = col >> 3, jj = col & 7;
    Wl[idx] = c.WhhT[k * 1024 + q * 256 + iw * 8 + jj];
  }
  for (int idx = tid; idx < 4096; idx += 256) {
    int b0 = idx >> 8, k0 = idx & 255;
    hl[b0 * 260 + k0] = c.enc_h[idx];
  }
  int b = tid >> 4, cg = tid & 15;
  int bu = tid >> 3, ju = tid & 7;
  float creg = 0.f;
  if (tid < 128) creg = c.enc_c[bu * 256 + iw * 8 + ju];
  __syncthreads();
  const float2* Wl2 = (const float2*)Wl;
  const float2* Gx2 = (const float2*)c.Gx;
  for (int t = 0; t < TT; ++t) {
    int q = cg >> 2;
    float2 acc = Gx2[(t * 16 + b) * 512 + q * 128 + iw * 4 + (cg & 3)];
#pragma unroll 4
    for (int k = 0; k < 256; ++k) {
      float hv = hl[b * 260 + k];
      float2 w = Wl2[k * 16 + cg];
      acc.x += hv * w.x; acc.y += hv * w.y;
    }
    ((float2*)(gs + b * 36 + 2 * cg))[0] = acc;
    __syncthreads();
    if (tid < 128) {
      float ig = gs[bu * 36 + ju];
      float fg = gs[bu * 36 + 8 + ju];
      float gg = gs[bu * 36 + 16 + ju];
      float og = gs[bu * 36 + 24 + ju];
      creg = sigf(fg) * creg + sigf(ig) * tanhf(gg);
      float hv = sigf(og) * tanhf(creg);
      int j = iw * 8 + ju;
      c.h_buf[((t + 1) & 1) * 4096 + bu * 256 + j] = hv;
      c.hs[(t * 16 + bu) * 256 + j] = hv;
    }
    __threadfence();
    __syncthreads();
    if (tid == 0) {
      __hip_atomic_fetch_add(c.bar, 1u, __ATOMIC_ACQ_REL, __HIP_MEMORY_SCOPE_AGENT);
      while (__hip_atomic_load(c.bar, __ATOMIC_ACQUIRE, __HIP_MEMORY_SCOPE_AGENT) < (unsigned)(32 * (t + 1)))
        __builtin_amdgcn_s_sleep(2);
      __threadfence();
    }
    __syncthreads();
    if (t < TT - 1) {
      int par = (t + 1) & 1;
      for (int idx = tid; idx < 4096; idx += 256) {
        int b0 = idx >> 8, k0 = idx & 255;
        hl[b0 * 260 + k0] = c.h_buf[par * 4096 + idx];
      }
      __syncthreads();
    }
  }
}

// ---------------- dec_proj = hs @ Ws^T + Ws_b ; hws = h.ws ----------------
__global__ void k_decproj(Ctx c) {
  int tb = blockIdx.x, tid = threadIdx.x;  // block 512
  __shared__ float h[256];
  __shared__ float red[256];
  if (tid < 256) h[tid] = c.hs[tb * 256 + tid];
  __syncthreads();
  float acc = c.Ws_b[tid];
#pragma unroll 4
  for (int k = 0; k < 256; ++k) acc += h[k] * c.WsT[k * 512 + tid];
  c.dec_proj[tb * 512 + tid] = acc;
  if (tid < 256) red[tid] = h[tid] * c.ws_w[tid];
  __syncthreads();
  for (int s = 128; s > 0; s >>= 1) { if (tid < 256 && tid < s) red[tid] += red[tid + s]; __syncthreads(); }
  if (tid == 0) c.hws[tb] = red[0];
}

// ---------------- enc_proj = enc_states @ Wh^T + Wh_b ----------------
__global__ void k_encproj(Ctx c) {
  int b = blockIdx.x / 100, lt = (blockIdx.x % 100) * 4, tid = threadIdx.x; // block 512
  __shared__ float es[4][512];
  for (int i = 0; i < 4; ++i) es[i][tid] = c.enc_states[(size_t)(b * LL + lt + i) * 512 + tid];
  __syncthreads();
  float bias = c.Wh_b[tid];
  float a0 = bias, a1 = bias, a2 = bias, a3 = bias;
#pragma unroll 4
  for (int k = 0; k < 512; ++k) {
    float w = c.WhT[k * 512 + tid];
    a0 += es[0][k] * w; a1 += es[1][k] * w; a2 += es[2][k] * w; a3 += es[3][k] * w;
  }
  c.enc_proj[(size_t)(b * LL + lt + 0) * 512 + tid] = a0;
  c.enc_proj[(size_t)(b * LL + lt + 1) * 512 + tid] = a1;
  c.enc_proj[(size_t)(b * LL + lt + 2) * 512 + tid] = a2;
  c.enc_proj[(size_t)(b * LL + lt + 3) * 512 + tid] = a3;
}

// ---------------- S1: attention scores (one wave per (b,l)) ----------------
__global__ void k_scores(Ctx c, int t) {
  int wv = blockIdx.x * 4 + (threadIdx.x >> 6);
  int lane = threadIdx.x & 63;
  int b = wv / 400, l = wv % 400;
  float cov = c.coverage[b * LL + l];
  const float* ep = c.enc_proj + (size_t)(b * LL + l) * 512;
  const float* dp = c.dec_proj + (size_t)(t * 16 + b) * 512;
  float acc = 0.f;
#pragma unroll
  for (int i = 0; i < 8; ++i) {
    int j = lane + 64 * i;
    float f = ep[j] + dp[j] + cov * c.wc_w[j] + c.wc_b[j];
    acc += tanhf(f) * c.v_w[j];
  }
  for (int off = 1; off < 64; off <<= 1) acc += __shfl_xor(acc, off, 64);
  if (lane == 0) {
    float s = acc + c.v_b[0];
    if (c.enc_mask[b * LL + l]) s = -1e30f;
    c.scores[b * LL + l] = s;
  }
}

// ---------------- S2: loss(t-1) + softmax + context + pgen + coverage + hcb ----------------
__global__ void k_step(Ctx c, int t) {
  int b = blockIdx.x, tid = threadIdx.x; // block 512
  __shared__ float red[512];
  __shared__ float attn_s[400];
  // Phase A: finish loss for step t-1 using tile pairs from k_vocab(t-1)
  if (t > 0) {
    float m = -FLT_MAX;
    for (int i = tid; i < NT; i += 512) m = fmaxf(m, c.pairs_m[b * NT + i]);
    red[tid] = m; __syncthreads();
    for (int s = 256; s > 0; s >>= 1) { if (tid < s) red[tid] = fmaxf(red[tid], red[tid + s]); __syncthreads(); }
    float M = red[0]; __syncthreads();
    float z = 0.f;
    for (int i = tid; i < NT; i += 512) z += c.pairs_s[b * NT + i] * expf(c.pairs_m[b * NT + i] - M);
    red[tid] = z; __syncthreads();
    for (int s = 256; s > 0; s >>= 1) { if (tid < s) red[tid] += red[tid + s]; __syncthreads(); }
    if (tid == 0) {
      int tgt = c.targets[b * TT + (t - 1)];
      if (tgt != 0) {
        float p = expf(c.logit_g[b] - M) / red[0];
        float pg = c.pgen[b];
        float o = pg * p + (1.f - pg) * c.attn_match[b];
        c.lm_sum[b] += -logf(o);
      }
    }
    __syncthreads();
  }
  // Phase B: softmax over L
  float sc = (tid < 400) ? c.scores[b * LL + tid] : -FLT_MAX;
  red[tid] = sc; __syncthreads();
  for (int s = 256; s > 0; s >>= 1) { if (tid < s) red[tid] = fmaxf(red[tid], red[tid + s]); __syncthreads(); }
  float M2 = red[0]; __syncthreads();
  float ex = (tid < 400) ? expf(sc - M2) : 0.f;
  red[tid] = ex; __syncthreads();
  for (int s = 256; s > 0; s >>= 1) { if (tid < s) red[tid] += red[tid + s]; __syncthreads(); }
  float S = red[0]; __syncthreads();
  float a = ex / S;
  if (tid < 400) attn_s[tid] = a;
  int tgt_t = c.targets[b * TT + t];
  int gidx = (tgt_t != 0) ? tgt_t - 1 : 0;
  float cvp = 0.f, mct = 0.f;
  if (tid < 400) {
    float nc = c.coverage[b * LL + tid] + a;
    c.coverage[b * LL + tid] = nc;
    cvp = fminf(nc, a);
    int idx = c.enc_mask[b * LL + tid] ? 0 : (c.article_inds[b * LL + tid] - 1);
    mct = (idx == gidx) ? a : 0.f;
  }
  red[tid] = cvp; __syncthreads();
  for (int s = 256; s > 0; s >>= 1) { if (tid < s) red[tid] += red[tid + s]; __syncthreads(); }
  if (tid == 0) c.covl_sum[b] += red[0];
  __syncthreads();
  red[tid] = mct; __syncthreads();
  for (int s = 256; s > 0; s >>= 1) { if (tid < s) red[tid] += red[tid + s]; __syncthreads(); }
  if (tid == 0) c.attn_match[b] = red[0];
  __syncthreads();
  // Phase C: context = attn @ enc_states ; write bf16 A-fragments hcb
  float ctx = 0.f;
#pragma unroll 4
  for (int l = 0; l < 400; ++l) ctx += attn_s[l] * c.enc_states[(size_t)(b * LL + l) * 512 + tid];
  // hcb chunked layout: element j of batch b -> hcb[(j>>3)*128 + b*8 + (j&7)]
  {
    int j = 256 + tid;
    c.hcb[(j >> 3) * 128 + b * 8 + (j & 7)] = f2bf(ctx);
    if (tid < 256) {
      float hv = c.hs[(t * 16 + b) * 256 + tid];
      c.hcb[(tid >> 3) * 128 + b * 8 + (tid & 7)] = f2bf(hv);
    }
  }
  // Phase D: p_gen
  red[tid] = ctx * c.wh_w[tid]; __syncthreads();
  for (int s = 256; s > 0; s >>= 1) { if (tid < s) red[tid] += red[tid + s]; __syncthreads(); }
  if (tid == 0) {
    float pg = red[0] + c.wh_b[0] + c.hws[t * 16 + b] + c.ws_b[0] + c.px[t * 16 + b] + c.wx_b[0];
    c.pgen[b] = sigf(pg);
  }
}

// ---------------- S3: vocab logits via MFMA bf16 -> per-tile online softmax pairs ----------------
// wave handles 16 vocab rows; lane: n=lane&15 (vocab row / A batch-row), q=lane>>4 (K-quad)
// D[m=batch=q*4+r][n=vocab] per m89 C/D layout.
__global__ void __launch_bounds__(256) k_vocab(Ctx c, int t) {
  int tid = threadIdx.x;
  int w = tid >> 6, lane = tid & 63;
  int n = lane & 15, q = lane >> 4;
  int base = blockIdx.x * 64 + w * 16;
  int row = base + n;
  int rowc = row < VOCAB ? row : VOCAB - 1;
  bool valid = (row < VOCAB);
  const bf16x8* A = (const bf16x8*)c.hcb;
  f32x4 acc = {0.f, 0.f, 0.f, 0.f};
  if (c.use_bf16) {
    const bf16x8* Bv = (const bf16x8*)c.Vb16;
    size_t brow = (size_t)rowc * 96;
#pragma unroll 4
    for (int ki = 0; ki < 24; ++ki) {
      bf16x8 af = A[(4 * ki + q) * 16 + n];
      bf16x8 bfr = Bv[brow + 4 * ki + q];
      acc = __builtin_amdgcn_mfma_f32_16x16x32_bf16(af, bfr, acc, 0, 0, 0);
    }
  } else {
    const float4* Bv = (const float4*)c.V_w;
    size_t brow = (size_t)rowc * 192;
#pragma unroll 2
    for (int ki = 0; ki < 24; ++ki) {
      bf16x8 af = A[(4 * ki + q) * 16 + n];
      float4 b0 = Bv[brow + ki * 8 + q * 2];
      float4 b1 = Bv[brow + ki * 8 + q * 2 + 1];
      bf16x8 bfr;
      bfr[0] = (short)f2bf(b0.x); bfr[1] = (short)f2bf(b0.y);
      bfr[2] = (short)f2bf(b0.z); bfr[3] = (short)f2bf(b0.w);
      bfr[4] = (short)f2bf(b1.x); bfr[5] = (short)f2bf(b1.y);
      bfr[6] = (short)f2bf(b1.z); bfr[7] = (short)f2bf(b1.w);
      acc = __builtin_amdgcn_mfma_f32_16x16x32_bf16(af, bfr, acc, 0, 0, 0);
    }
  }
  // epilogue: add bias, capture target logits, 16-lane online-softmax reduce
  float vb = c.V_b[rowc];
  float m4[4], s4[4];
#pragma unroll
  for (int r = 0; r < 4; ++r) {
    float lg = acc[r] + vb;
    if (valid) {
      m4[r] = lg; s4[r] = 1.f;
      int b = q * 4 + r;
      int tgt = c.targets[b * TT + t];
      int gi = (tgt != 0) ? tgt - 1 : 0;
      if (gi == row) c.logit_g[b] = lg;
    } else { m4[r] = -FLT_MAX; s4[r] = 0.f; }
  }
#pragma unroll
  for (int off = 1; off < 16; off <<= 1) {
#pragma unroll
    for (int r = 0; r < 4; ++r) {
      float om = __shfl_xor(m4[r], off, 16);
      float os = __shfl_xor(s4[r], off, 16);
      float M = fmaxf(m4[r], om);
      s4[r] = s4[r] * expf(m4[r] - M) + os * expf(om - M);
      m4[r] = M;
    }
  }
  if (n == 0) {
    int tile = blockIdx.x * 4 + w;
#pragma unroll
    for (int r = 0; r < 4; ++r) {
      c.pairs_m[(q * 4 + r) * NT + tile] = m4[r];
      c.pairs_s[(q * 4 + r) * NT + tile] = s4[r];
    }
  }
}

// ---------------- finalize: loss for t=39 + output ----------------
__global__ void k_final(Ctx c) {
  int b = blockIdx.x, tid = threadIdx.x; // block 512
  __shared__ float red[512];
  float m = -FLT_MAX;
  for (int i = tid; i < NT; i += 512) m = fmaxf(m, c.pairs_m[b * NT + i]);
  red[tid] = m; __syncthreads();
  for (int s = 256; s > 0; s >>= 1) { if (tid < s) red[tid] = fmaxf(red[tid], red[tid + s]); __syncthreads(); }
  float M = red[0]; __syncthreads();
  float z = 0.f;
  for (int i = tid; i < NT; i += 512) z += c.pairs_s[b * NT + i] * expf(c.pairs_m[b * NT + i] - M);
  red[tid] = z; __syncthreads();
  for (int s = 256; s > 0; s >>= 1) { if (tid < s) red[tid] += red[tid + s]; __syncthreads(); }
  float Z = red[0]; __syncthreads();
  float dl = (tid < TT && c.dec_input[b * TT + tid] > 0) ? 1.f : 0.f;
  red[tid] = dl; __syncthreads();
  for (int s = 256; s > 0; s >>= 1) { if (tid < s) red[tid] += red[tid + s]; __syncthreads(); }
  if (tid == 0) {
    float dlen = red[0];
    int tgt = c.targets[b * TT + 39];
    float lm39 = 0.f;
    if (tgt != 0) {
      float p = expf(c.logit_g[b] - M) / Z;
      float pg = c.pgen[b];
      lm39 = -logf(pg * p + (1.f - pg) * c.attn_match[b]);
    }
    c.out[b] = (c.lm_sum[b] + lm39) / dlen + c.covl_sum[b] / dlen;
  }
}

extern "C" void kernel_launch(void* const* d_in, const int* in_sizes, int n_in,
                              void* d_out, int out_size, void* d_ws, size_t ws_size,
                              hipStream_t stream) {
  Ctx c;
  c.enc_states = (const float*)d_in[0];
  c.enc_h      = (const float*)d_in[1];
  c.enc_c      = (const float*)d_in[2];
  c.embed      = (const float*)d_in[3];
  c.Wih        = (const float*)d_in[4];
  c.Whh        = (const float*)d_in[5];
  c.bih        = (const float*)d_in[6];
  c.bhh        = (const float*)d_in[7];
  c.Wh_w       = (const float*)d_in[8];
  c.Wh_b       = (const float*)d_in[9];
  c.Ws_w       = (const float*)d_in[10];
  c.Ws_b       = (const float*)d_in[11];
  c.wc_w       = (const float*)d_in[12];
  c.wc_b       = (const float*)d_in[13];
  c.v_w        = (const float*)d_in[14];
  c.v_b        = (const float*)d_in[15];
  c.wh_w       = (const float*)d_in[16];
  c.wh_b       = (const float*)d_in[17];
  c.ws_w       = (const float*)d_in[18];
  c.ws_b       = (const float*)d_in[19];
  c.wx_w       = (const float*)d_in[20];
  c.wx_b       = (const float*)d_in[21];
  c.V_w        = (const float*)d_in[22];
  c.V_b        = (const float*)d_in[23];
  c.dec_input  = (const int*)d_in[24];
  c.targets    = (const int*)d_in[25];
  c.article_inds = (const int*)d_in[26];
  c.enc_mask   = (const unsigned char*)d_in[27];

  float* p = (float*)d_ws;
  c.Gx = p;        p += TT * BB * 1024;
  c.hs = p;        p += TT * BB * 256;
  c.dec_proj = p;  p += TT * BB * 512;
  c.enc_proj = p;  p += (size_t)BB * LL * 512;
  c.WihT = p;      p += 1024 * 256;
  c.WhhT = p;      p += 1024 * 256;
  c.WsT = p;       p += 512 * 256;
  c.WhT = p;       p += 512 * 512;
  c.coverage = p;  p += BB * LL;
  c.scores = p;    p += BB * LL;
  c.hcb = (unsigned short*)p; p += BB * 768 / 2;   // 12288 bf16 = 6144 floats
  c.pairs_m = p;   p += BB * NT;
  c.pairs_s = p;   p += BB * NT;
  c.px = p;        p += TT * BB;
  c.hws = p;       p += TT * BB;
  c.pgen = p;        p += 16;
  c.attn_match = p;  p += 16;
  c.logit_g = p;     p += 16;
  c.lm_sum = p;      p += 16;
  c.covl_sum = p;    p += 16;
  c.h_buf = p;       p += 2 * BB * 256;
  c.bar = (unsigned*)p; p += 16;
  c.Vb16 = (unsigned short*)p;
  size_t used_bytes = (size_t)((char*)p - (char*)d_ws);
  size_t vb16_bytes = (size_t)VOCAB * 768 * 2;
  c.use_bf16 = (used_bytes + vb16_bytes <= ws_size) ? 1 : 0;
  c.out = (float*)d_out;

  k_init<<<26, 256, 0, stream>>>(c);
  if (c.use_bf16) k_cvt<<<1024, 256, 0, stream>>>(c.V_w, c.Vb16, VOCAB * 768 / 8);
  k_transpose<<<dim3(8, 32), dim3(32, 8), 0, stream>>>(c.Wih, c.WihT, 1024, 256);
  k_transpose<<<dim3(8, 32), dim3(32, 8), 0, stream>>>(c.Whh, c.WhhT, 1024, 256);
  k_transpose<<<dim3(8, 16), dim3(32, 8), 0, stream>>>(c.Ws_w, c.WsT, 512, 256);
  k_transpose<<<dim3(16, 16), dim3(32, 8), 0, stream>>>(c.Wh_w, c.WhT, 512, 512);
  k_gx<<<TT * BB, 256, 0, stream>>>(c);
  k_encproj<<<16 * 100, 512, 0, stream>>>(c);
  k_lstm<<<32, 256, 0, stream>>>(c);
  k_decproj<<<TT * BB, 512, 0, stream>>>(c);
  for (int t = 0; t < TT; ++t) {
    k_scores<<<1600, 256, 0, stream>>>(c, t);
    k_step<<<16, 512, 0, stream>>>(c, t);
    k_vocab<<<782, 256, 0, stream>>>(c, t);
  }
  k_final<<<16, 512, 0, stream>>>(c);
}

// Round 3
// 2033.467 us; speedup vs baseline: 4.1574x; 1.7474x over previous
//
#include <hip/hip_runtime.h>
#include <float.h>
#include <math.h>

// Problem constants
#define BB 16
#define LL 400
#define TT 40
#define HH 256
#define EE 256
#define VOCAB 50000
#define NBLK 782          // vocab n-blocks of 64 cols
#define NBW (NBLK * 2)    // pairs width: 2 n-subtiles of 32 per block

typedef __attribute__((ext_vector_type(8))) short bf16x8;
typedef __attribute__((ext_vector_type(4))) float f32x4;
typedef __attribute__((ext_vector_type(8))) unsigned short ushort8;

struct Ctx {
  // inputs
  const float *enc_states, *enc_h, *enc_c, *embed;
  const float *Wih, *Whh, *bih, *bhh;
  const float *Wh_w, *Wh_b, *Ws_w, *Ws_b;
  const float *wc_w, *wc_b, *v_w, *v_b;
  const float *wh_w, *wh_b, *ws_w, *ws_b, *wx_w, *wx_b;
  const float *V_w, *V_b;
  const int *dec_input, *targets, *article_inds;
  const unsigned char *enc_mask;
  // workspace
  float *Gx;        // [T,B,1024]
  float *hs;        // [T,B,256]
  float *dec_proj;  // [T,B,512]
  float *enc_proj;  // [B,L,512]
  float *WihT, *WsT, *WhT;
  float *coverage;  // [B,L]
  float *scores;    // [B,L]
  unsigned short *hcbA; // [T][96][16][8] bf16 A-fragments of concat(h,ctx), all steps
  float *pairs_m, *pairs_s;  // [640][NBW]
  float *px, *hws;  // [T*B]
  float *pgenA, *attnA, *logitA, *lmA; // [640]
  float *covl_sum;  // [16]
  unsigned short *hbuf_hi, *hbuf_lo;  // [2][4096] LSTM h exchange (bf16 hi/lo, frag layout)
  unsigned *bar;
  unsigned short *Vb16;  // [50000][768] bf16 V_w (optional)
  int use_bf16;
  float *out;       // [B]
};

__device__ __forceinline__ float sigf(float x) { return 1.f / (1.f + expf(-x)); }

__device__ __forceinline__ unsigned short f2bf(float x) {
  unsigned u = __builtin_bit_cast(unsigned, x);
  u = (u + 0x7FFFu + ((u >> 16) & 1u)) >> 16;
  return (unsigned short)u;
}
__device__ __forceinline__ float bf2f(unsigned short h) {
  unsigned u = ((unsigned)h) << 16;
  return __builtin_bit_cast(float, u);
}

// ---------------- init ----------------
__global__ void k_init(Ctx c) {
  int i = blockIdx.x * 256 + threadIdx.x;
  if (i < BB * LL) c.coverage[i] = 0.f;
  if (i < BB) c.covl_sum[i] = 0.f;
  if (i == 0) *c.bar = 0u;
}

// ---------------- V_w fp32 -> bf16 ----------------
__global__ void k_cvt(const float* __restrict__ src, unsigned short* __restrict__ dst, int ngroups) {
  int i = blockIdx.x * 256 + threadIdx.x;
  int stride = gridDim.x * 256;
  const float4* s4 = (const float4*)src;
  ushort8* d8 = (ushort8*)dst;
  for (; i < ngroups; i += stride) {
    float4 a = s4[2 * i], b = s4[2 * i + 1];
    ushort8 o;
    o[0] = f2bf(a.x); o[1] = f2bf(a.y); o[2] = f2bf(a.z); o[3] = f2bf(a.w);
    o[4] = f2bf(b.x); o[5] = f2bf(b.y); o[6] = f2bf(b.z); o[7] = f2bf(b.w);
    d8[i] = o;
  }
}

// ---------------- tiled transpose: in[R][C] -> out[C][R] ----------------
__global__ void k_transpose(const float* __restrict__ in, float* __restrict__ out, int R, int C) {
  __shared__ float tile[32][33];
  int bx = blockIdx.x * 32, by = blockIdx.y * 32;
  int tx = threadIdx.x, ty = threadIdx.y;
  for (int i = ty; i < 32; i += 8) tile[i][tx] = in[(by + i) * C + bx + tx];
  __syncthreads();
  for (int i = ty; i < 32; i += 8) out[(bx + i) * R + by + tx] = tile[tx][i];
}

// ---------------- Gx = embed[dec_input] @ Wih^T + bih + bhh ; px = e.wx ----------------
__global__ void k_gx(Ctx c) {
  int tb = blockIdx.x;
  int t = tb >> 4, b = tb & 15;
  int tid = threadIdx.x;          // 256
  __shared__ float x[EE];
  __shared__ float red[256];
  int tok = c.dec_input[b * TT + t];
  x[tid] = c.embed[(size_t)tok * EE + tid];
  __syncthreads();
  const float4* WT4 = (const float4*)c.WihT;
  float4 acc = ((const float4*)c.bih)[tid];
  float4 b2 = ((const float4*)c.bhh)[tid];
  acc.x += b2.x; acc.y += b2.y; acc.z += b2.z; acc.w += b2.w;
#pragma unroll 4
  for (int k = 0; k < EE; ++k) {
    float xv = x[k];
    float4 w = WT4[k * 256 + tid];
    acc.x += xv * w.x; acc.y += xv * w.y; acc.z += xv * w.z; acc.w += xv * w.w;
  }
  ((float4*)c.Gx)[tb * 256 + tid] = acc;
  red[tid] = x[tid] * c.wx_w[tid];
  __syncthreads();
  for (int s = 128; s > 0; s >>= 1) { if (tid < s) red[tid] += red[tid + s]; __syncthreads(); }
  if (tid == 0) c.px[tb] = red[0];
}

// ---------------- persistent MFMA LSTM: 16 WGs, Whh split-bf16 in VGPRs ----------------
// WG w owns hidden j in [w*16, w*16+16); wave g = gate (i,f,g,o).
// Wave g's MFMA cols = g*256 + w*16 + (lane&15).
__global__ void __launch_bounds__(256) k_lstm(Ctx c) {
  __shared__ unsigned short hAhi[4096], hAlo[4096];  // A-frag layout [kc4q4][b16][8]
  __shared__ float gs[4][16][16];
  int w = blockIdx.x, tid = threadIdx.x;
  int g = tid >> 6, lane = tid & 63;
  int n = lane & 15, q = lane >> 4;
  // preload B-frags (Whh rows) split hi/lo
  bf16x8 Bhi[8], Blo[8];
  {
    const float* wr = c.Whh + (size_t)(g * 256 + w * 16 + n) * 256;
#pragma unroll
    for (int kc = 0; kc < 8; ++kc) {
      const float* p8 = wr + kc * 32 + q * 8;
#pragma unroll
      for (int j = 0; j < 8; ++j) {
        float x = p8[j];
        unsigned short hi = f2bf(x);
        unsigned short lo = f2bf(x - bf2f(hi));
        Bhi[kc][j] = (short)hi; Blo[kc][j] = (short)lo;
      }
    }
  }
  // stage h0 into LDS A-frag layout
  for (int idx = tid; idx < 4096; idx += 256) {
    int b = idx >> 8, k = idx & 255;
    float x = c.enc_h[idx];
    unsigned short hi = f2bf(x);
    unsigned short lo = f2bf(x - bf2f(hi));
    int pos = (((k >> 5) * 4 + ((k >> 3) & 3)) * 16 + b) * 8 + (k & 7);
    hAhi[pos] = hi; hAlo[pos] = lo;
  }
  int bu = tid >> 4, ju = tid & 15;
  float creg = c.enc_c[bu * 256 + w * 16 + ju];
  __syncthreads();
  const bf16x8* Ahi = (const bf16x8*)hAhi;
  const bf16x8* Alo = (const bf16x8*)hAlo;
  int col = g * 256 + w * 16 + n;
  for (int t = 0; t < TT; ++t) {
    // D init from Gx (fp32, full precision)
    const float* gxp = c.Gx + (size_t)(t * 16) * 1024 + col;
    f32x4 acc;
    acc[0] = gxp[(q * 4 + 0) * 1024]; acc[1] = gxp[(q * 4 + 1) * 1024];
    acc[2] = gxp[(q * 4 + 2) * 1024]; acc[3] = gxp[(q * 4 + 3) * 1024];
#pragma unroll
    for (int kc = 0; kc < 8; ++kc) {
      bf16x8 ah = Ahi[(kc * 4 + q) * 16 + n];
      bf16x8 al = Alo[(kc * 4 + q) * 16 + n];
      acc = __builtin_amdgcn_mfma_f32_16x16x32_bf16(ah, Bhi[kc], acc, 0, 0, 0);
      acc = __builtin_amdgcn_mfma_f32_16x16x32_bf16(al, Bhi[kc], acc, 0, 0, 0);
      acc = __builtin_amdgcn_mfma_f32_16x16x32_bf16(ah, Blo[kc], acc, 0, 0, 0);
    }
#pragma unroll
    for (int r = 0; r < 4; ++r) gs[g][q * 4 + r][n] = acc[r];
    __syncthreads();
    // gate update (all 256 threads: one (b, j) each)
    {
      float ig = gs[0][bu][ju], fg = gs[1][bu][ju], gg = gs[2][bu][ju], og = gs[3][bu][ju];
      creg = sigf(fg) * creg + sigf(ig) * tanhf(gg);
      float hv = sigf(og) * tanhf(creg);
      int j = w * 16 + ju;
      c.hs[(t * 16 + bu) * 256 + j] = hv;
      unsigned short hi = f2bf(hv);
      unsigned short lo = f2bf(hv - bf2f(hi));
      int pos = (((j >> 5) * 4 + ((j >> 3) & 3)) * 16 + bu) * 8 + (j & 7);
      int par = (t + 1) & 1;
      c.hbuf_hi[par * 4096 + pos] = hi;
      c.hbuf_lo[par * 4096 + pos] = lo;
    }
    __threadfence();
    __syncthreads();
    if (tid == 0) {
      __hip_atomic_fetch_add(c.bar, 1u, __ATOMIC_ACQ_REL, __HIP_MEMORY_SCOPE_AGENT);
      while (__hip_atomic_load(c.bar, __ATOMIC_ACQUIRE, __HIP_MEMORY_SCOPE_AGENT) < (unsigned)(16 * (t + 1)))
        __builtin_amdgcn_s_sleep(2);
      __threadfence();
    }
    __syncthreads();
    if (t < TT - 1) {
      int par = (t + 1) & 1;
      for (int idx = tid; idx < 4096; idx += 256) {
        hAhi[idx] = c.hbuf_hi[par * 4096 + idx];
        hAlo[idx] = c.hbuf_lo[par * 4096 + idx];
      }
      __syncthreads();
    }
  }
}

// ---------------- dec_proj = hs @ Ws^T + Ws_b ; hws = h.ws ----------------
__global__ void k_decproj(Ctx c) {
  int tb = blockIdx.x, tid = threadIdx.x;  // block 512
  __shared__ float h[256];
  __shared__ float red[256];
  if (tid < 256) h[tid] = c.hs[tb * 256 + tid];
  __syncthreads();
  float acc = c.Ws_b[tid];
#pragma unroll 4
  for (int k = 0; k < 256; ++k) acc += h[k] * c.WsT[k * 512 + tid];
  c.dec_proj[tb * 512 + tid] = acc;
  if (tid < 256) red[tid] = h[tid] * c.ws_w[tid];
  __syncthreads();
  for (int s = 128; s > 0; s >>= 1) { if (tid < 256 && tid < s) red[tid] += red[tid + s]; __syncthreads(); }
  if (tid == 0) c.hws[tb] = red[0];
}

// ---------------- enc_proj = enc_states @ Wh^T + Wh_b ----------------
__global__ void k_encproj(Ctx c) {
  int b = blockIdx.x / 100, lt = (blockIdx.x % 100) * 4, tid = threadIdx.x; // block 512
  __shared__ float es[4][512];
  for (int i = 0; i < 4; ++i) es[i][tid] = c.enc_states[(size_t)(b * LL + lt + i) * 512 + tid];
  __syncthreads();
  float bias = c.Wh_b[tid];
  float a0 = bias, a1 = bias, a2 = bias, a3 = bias;
#pragma unroll 4
  for (int k = 0; k < 512; ++k) {
    float w = c.WhT[k * 512 + tid];
    a0 += es[0][k] * w; a1 += es[1][k] * w; a2 += es[2][k] * w; a3 += es[3][k] * w;
  }
  c.enc_proj[(size_t)(b * LL + lt + 0) * 512 + tid] = a0;
  c.enc_proj[(size_t)(b * LL + lt + 1) * 512 + tid] = a1;
  c.enc_proj[(size_t)(b * LL + lt + 2) * 512 + tid] = a2;
  c.enc_proj[(size_t)(b * LL + lt + 3) * 512 + tid] = a3;
}

// ---------------- S1: attention scores ----------------
__global__ void k_scores(Ctx c, int t) {
  int wv = blockIdx.x * 4 + (threadIdx.x >> 6);
  int lane = threadIdx.x & 63;
  int b = wv / 400, l = wv % 400;
  float cov = c.coverage[b * LL + l];
  const float* ep = c.enc_proj + (size_t)(b * LL + l) * 512;
  const float* dp = c.dec_proj + (size_t)(t * 16 + b) * 512;
  float acc = 0.f;
#pragma unroll
  for (int i = 0; i < 8; ++i) {
    int j = lane + 64 * i;
    float f = ep[j] + dp[j] + cov * c.wc_w[j] + c.wc_b[j];
    acc += tanhf(f) * c.v_w[j];
  }
  for (int off = 1; off < 64; off <<= 1) acc += __shfl_xor(acc, off, 64);
  if (lane == 0) {
    float s = acc + c.v_b[0];
    if (c.enc_mask[b * LL + l]) s = -1e30f;
    c.scores[b * LL + l] = s;
  }
}

// ---------------- S2: softmax + coverage + context + pgen + hcbA archive ----------------
__global__ void __launch_bounds__(1024) k_step(Ctx c, int t) {
  int b = blockIdx.x, tid = threadIdx.x; // block 1024
  __shared__ float red[1024];
  __shared__ float attn_s[400];
  // softmax over L
  float sc = (tid < 400) ? c.scores[b * LL + tid] : -FLT_MAX;
  red[tid] = sc; __syncthreads();
  for (int s = 512; s > 0; s >>= 1) { if (tid < s) red[tid] = fmaxf(red[tid], red[tid + s]); __syncthreads(); }
  float M2 = red[0]; __syncthreads();
  float ex = (tid < 400) ? __expf(sc - M2) : 0.f;
  red[tid] = ex; __syncthreads();
  for (int s = 512; s > 0; s >>= 1) { if (tid < s) red[tid] += red[tid + s]; __syncthreads(); }
  float S = red[0]; __syncthreads();
  float a = ex / S;
  if (tid < 400) attn_s[tid] = a;
  // coverage + covl + attn-match
  int tgt_t = c.targets[b * TT + t];
  int gidx = (tgt_t != 0) ? tgt_t - 1 : 0;
  float cvp = 0.f, mct = 0.f;
  if (tid < 400) {
    float nc = c.coverage[b * LL + tid] + a;
    c.coverage[b * LL + tid] = nc;
    cvp = fminf(nc, a);
    int idx = c.enc_mask[b * LL + tid] ? 0 : (c.article_inds[b * LL + tid] - 1);
    mct = (idx == gidx) ? a : 0.f;
  }
  red[tid] = cvp; __syncthreads();
  for (int s = 512; s > 0; s >>= 1) { if (tid < s) red[tid] += red[tid + s]; __syncthreads(); }
  if (tid == 0) c.covl_sum[b] += red[0];
  __syncthreads();
  red[tid] = mct; __syncthreads();
  for (int s = 512; s > 0; s >>= 1) { if (tid < s) red[tid] += red[tid + s]; __syncthreads(); }
  if (tid == 0) c.attnA[t * 16 + b] = red[0];
  __syncthreads();
  // context, 2-way l-split
  int j = tid & 511, half = tid >> 9;
  float part = 0.f;
  {
    const float* esb = c.enc_states + (size_t)b * LL * 512 + j;
    int l0 = half * 200;
#pragma unroll 4
    for (int l = l0; l < l0 + 200; ++l) part += attn_s[l] * esb[(size_t)l * 512];
  }
  red[tid] = part; __syncthreads();
  float ctx = 0.f;
  unsigned short* hct = c.hcbA + (size_t)t * 12288;
  if (tid < 512) {
    ctx = red[tid] + red[tid + 512];
    int jj = 256 + j;
    hct[(jj >> 3) * 128 + b * 8 + (jj & 7)] = f2bf(ctx);
    if (tid < 256) {
      float hv = c.hs[(t * 16 + b) * 256 + tid];
      hct[(tid >> 3) * 128 + b * 8 + (tid & 7)] = f2bf(hv);
    }
  }
  __syncthreads();
  red[tid] = (tid < 512) ? ctx * c.wh_w[j] : 0.f;
  __syncthreads();
  for (int s = 512; s > 0; s >>= 1) { if (tid < s) red[tid] += red[tid + s]; __syncthreads(); }
  if (tid == 0) {
    float pg = red[0] + c.wh_b[0] + c.hws[t * 16 + b] + c.ws_b[0] + c.px[t * 16 + b] + c.wx_b[0];
    c.pgenA[t * 16 + b] = sigf(pg);
  }
}

// ---------------- one-shot vocab GEMM: [640,768] @ [768,50000] -> online-softmax pairs ----------------
// Block: 64 vocab cols, 256 threads = 4 waves (mh in {0,1} m-half of 20 t, np in {0,1} 32-col pair).
// B streamed from global (read once), A-chunks staged in LDS, D in registers (40 f32x4/wave).
__global__ void __launch_bounds__(256) k_vocab_all(Ctx c) {
  __shared__ unsigned short As[40 * 512];   // [t40][q4][b16][8] bf16 for current kc
  __shared__ int gidxs[640];
  int tid = threadIdx.x;
  int wv = tid >> 6, lane = tid & 63;
  int mh = wv >> 1, np = wv & 1;
  int n = lane & 15, q = lane >> 4;
  for (int i = tid; i < 640; i += 256) {
    int t = i >> 4, b = i & 15;
    int tg = c.targets[b * TT + t];
    gidxs[i] = (tg != 0) ? tg - 1 : 0;
  }
  int col0 = blockIdx.x * 64 + np * 32 + n;
  int col1 = col0 + 16;
  bool v0 = col0 < VOCAB, v1 = col1 < VOCAB;
  int col0c = v0 ? col0 : 0, col1c = v1 ? col1 : 0;
  float vb0 = c.V_b[col0c], vb1 = c.V_b[col1c];
  f32x4 D0[20], D1[20];
#pragma unroll
  for (int i = 0; i < 20; ++i) { D0[i] = (f32x4){0.f,0.f,0.f,0.f}; D1[i] = (f32x4){0.f,0.f,0.f,0.f}; }
  const ushort8* srcA = (const ushort8*)c.hcbA;
  ushort8* dstA = (ushort8*)As;
  const bf16x8* A8 = (const bf16x8*)As;
  for (int kc = 0; kc < 24; ++kc) {
    __syncthreads();
    for (int u = tid; u < 2560; u += 256) {
      int t = u >> 6, r = u & 63;
      dstA[u] = srcA[(size_t)t * 1536 + kc * 64 + r];
    }
    __syncthreads();
    bf16x8 B0, B1;
    if (c.use_bf16) {
      B0 = *(const bf16x8*)(c.Vb16 + (size_t)col0c * 768 + kc * 32 + q * 8);
      B1 = *(const bf16x8*)(c.Vb16 + (size_t)col1c * 768 + kc * 32 + q * 8);
    } else {
      const float4* r0 = (const float4*)(c.V_w + (size_t)col0c * 768 + kc * 32 + q * 8);
      const float4* r1 = (const float4*)(c.V_w + (size_t)col1c * 768 + kc * 32 + q * 8);
      float4 a0 = r0[0], a1 = r0[1], b0 = r1[0], b1 = r1[1];
      B0[0]=(short)f2bf(a0.x); B0[1]=(short)f2bf(a0.y); B0[2]=(short)f2bf(a0.z); B0[3]=(short)f2bf(a0.w);
      B0[4]=(short)f2bf(a1.x); B0[5]=(short)f2bf(a1.y); B0[6]=(short)f2bf(a1.z); B0[7]=(short)f2bf(a1.w);
      B1[0]=(short)f2bf(b0.x); B1[1]=(short)f2bf(b0.y); B1[2]=(short)f2bf(b0.z); B1[3]=(short)f2bf(b0.w);
      B1[4]=(short)f2bf(b1.x); B1[5]=(short)f2bf(b1.y); B1[6]=(short)f2bf(b1.z); B1[7]=(short)f2bf(b1.w);
    }
#pragma unroll
    for (int i = 0; i < 20; ++i) {
      int mt = mh * 20 + i;
      bf16x8 a = A8[mt * 64 + q * 16 + n];
      D0[i] = __builtin_amdgcn_mfma_f32_16x16x32_bf16(a, B0, D0[i], 0, 0, 0);
      D1[i] = __builtin_amdgcn_mfma_f32_16x16x32_bf16(a, B1, D1[i], 0, 0, 0);
    }
  }
  // epilogue: bias + target logits + per-(t,b) online softmax over this wave's 32 cols
#pragma unroll
  for (int i = 0; i < 20; ++i) {
    int t = mh * 20 + i;
#pragma unroll
    for (int r = 0; r < 4; ++r) {
      int b = q * 4 + r;
      float lg0 = D0[i][r] + vb0, lg1 = D1[i][r] + vb1;
      int gi = gidxs[t * 16 + b];
      if (v0 && col0 == gi) c.logitA[t * 16 + b] = lg0;
      if (v1 && col1 == gi) c.logitA[t * 16 + b] = lg1;
      float e0 = v0 ? lg0 : -FLT_MAX, e1 = v1 ? lg1 : -FLT_MAX;
      float m_ = fmaxf(e0, e1);
      float s_ = (v0 ? __expf(lg0 - m_) : 0.f) + (v1 ? __expf(lg1 - m_) : 0.f);
#pragma unroll
      for (int off = 1; off < 16; off <<= 1) {
        float om = __shfl_xor(m_, off, 16);
        float os = __shfl_xor(s_, off, 16);
        float M = fmaxf(m_, om);
        s_ = s_ * __expf(m_ - M) + os * __expf(om - M);
        m_ = M;
      }
      if (n == 0) {
        int pc = blockIdx.x * 2 + np;
        c.pairs_m[(size_t)(t * 16 + b) * NBW + pc] = m_;
        c.pairs_s[(size_t)(t * 16 + b) * NBW + pc] = s_;
      }
    }
  }
}

// ---------------- per-(t,b) loss from pairs ----------------
__global__ void k_final_all(Ctx c) {
  int row = blockIdx.x;  // t*16 + b
  int tid = threadIdx.x; // 256
  __shared__ float red[256];
  float m = -FLT_MAX;
  for (int i = tid; i < NBW; i += 256) m = fmaxf(m, c.pairs_m[(size_t)row * NBW + i]);
  red[tid] = m; __syncthreads();
  for (int s = 128; s > 0; s >>= 1) { if (tid < s) red[tid] = fmaxf(red[tid], red[tid + s]); __syncthreads(); }
  float M = red[0]; __syncthreads();
  float z = 0.f;
  for (int i = tid; i < NBW; i += 256)
    z += c.pairs_s[(size_t)row * NBW + i] * __expf(c.pairs_m[(size_t)row * NBW + i] - M);
  red[tid] = z; __syncthreads();
  for (int s = 128; s > 0; s >>= 1) { if (tid < s) red[tid] += red[tid + s]; __syncthreads(); }
  if (tid == 0) {
    int t = row >> 4, b = row & 15;
    int tgt = c.targets[b * TT + t];
    float lm = 0.f;
    if (tgt != 0) {
      float p = __expf(c.logitA[row] - M) / red[0];
      float pg = c.pgenA[row];
      lm = -logf(pg * p + (1.f - pg) * c.attnA[row]);
    }
    c.lmA[row] = lm;
  }
}

// ---------------- output ----------------
__global__ void k_out(Ctx c) {
  int b = blockIdx.x, tid = threadIdx.x; // 64 threads
  float lm = (tid < TT) ? c.lmA[tid * 16 + b] : 0.f;
  float dl = (tid < TT && c.dec_input[b * TT + tid] > 0) ? 1.f : 0.f;
  for (int off = 1; off < 64; off <<= 1) {
    lm += __shfl_xor(lm, off, 64);
    dl += __shfl_xor(dl, off, 64);
  }
  if (tid == 0) c.out[b] = lm / dl + c.covl_sum[b] / dl;
}

extern "C" void kernel_launch(void* const* d_in, const int* in_sizes, int n_in,
                              void* d_out, int out_size, void* d_ws, size_t ws_size,
                              hipStream_t stream) {
  Ctx c;
  c.enc_states = (const float*)d_in[0];
  c.enc_h      = (const float*)d_in[1];
  c.enc_c      = (const float*)d_in[2];
  c.embed      = (const float*)d_in[3];
  c.Wih        = (const float*)d_in[4];
  c.Whh        = (const float*)d_in[5];
  c.bih        = (const float*)d_in[6];
  c.bhh        = (const float*)d_in[7];
  c.Wh_w       = (const float*)d_in[8];
  c.Wh_b       = (const float*)d_in[9];
  c.Ws_w       = (const float*)d_in[10];
  c.Ws_b       = (const float*)d_in[11];
  c.wc_w       = (const float*)d_in[12];
  c.wc_b       = (const float*)d_in[13];
  c.v_w        = (const float*)d_in[14];
  c.v_b        = (const float*)d_in[15];
  c.wh_w       = (const float*)d_in[16];
  c.wh_b       = (const float*)d_in[17];
  c.ws_w       = (const float*)d_in[18];
  c.ws_b       = (const float*)d_in[19];
  c.wx_w       = (const float*)d_in[20];
  c.wx_b       = (const float*)d_in[21];
  c.V_w        = (const float*)d_in[22];
  c.V_b        = (const float*)d_in[23];
  c.dec_input  = (const int*)d_in[24];
  c.targets    = (const int*)d_in[25];
  c.article_inds = (const int*)d_in[26];
  c.enc_mask   = (const unsigned char*)d_in[27];

  float* p = (float*)d_ws;
  c.Gx = p;        p += TT * BB * 1024;
  c.hs = p;        p += TT * BB * 256;
  c.dec_proj = p;  p += TT * BB * 512;
  c.enc_proj = p;  p += (size_t)BB * LL * 512;
  c.WihT = p;      p += 1024 * 256;
  c.WsT = p;       p += 512 * 256;
  c.WhT = p;       p += 512 * 512;
  c.coverage = p;  p += BB * LL;
  c.scores = p;    p += BB * LL;
  c.hcbA = (unsigned short*)p; p += TT * BB * 768 / 2;
  c.pairs_m = p;   p += (size_t)640 * NBW;
  c.pairs_s = p;   p += (size_t)640 * NBW;
  c.px = p;        p += TT * BB;
  c.hws = p;       p += TT * BB;
  c.pgenA = p;     p += 640;
  c.attnA = p;     p += 640;
  c.logitA = p;    p += 640;
  c.lmA = p;       p += 640;
  c.covl_sum = p;  p += 16;
  c.hbuf_hi = (unsigned short*)p; p += 2 * 4096 / 2;
  c.hbuf_lo = (unsigned short*)p; p += 2 * 4096 / 2;
  c.bar = (unsigned*)p; p += 16;
  c.Vb16 = (unsigned short*)p;
  size_t used_bytes = (size_t)((char*)p - (char*)d_ws);
  size_t vb16_bytes = (size_t)VOCAB * 768 * 2;
  c.use_bf16 = (used_bytes + vb16_bytes <= ws_size) ? 1 : 0;
  c.out = (float*)d_out;

  k_init<<<26, 256, 0, stream>>>(c);
  if (c.use_bf16) k_cvt<<<1024, 256, 0, stream>>>(c.V_w, c.Vb16, VOCAB * 768 / 8);
  k_transpose<<<dim3(8, 32), dim3(32, 8), 0, stream>>>(c.Wih, c.WihT, 1024, 256);
  k_transpose<<<dim3(8, 16), dim3(32, 8), 0, stream>>>(c.Ws_w, c.WsT, 512, 256);
  k_transpose<<<dim3(16, 16), dim3(32, 8), 0, stream>>>(c.Wh_w, c.WhT, 512, 512);
  k_gx<<<TT * BB, 256, 0, stream>>>(c);
  k_encproj<<<16 * 100, 512, 0, stream>>>(c);
  k_lstm<<<16, 256, 0, stream>>>(c);
  k_decproj<<<TT * BB, 512, 0, stream>>>(c);
  for (int t = 0; t < TT; ++t) {
    k_scores<<<1600, 256, 0, stream>>>(c, t);
    k_step<<<16, 1024, 0, stream>>>(c, t);
  }
  k_vocab_all<<<NBLK, 256, 0, stream>>>(c);
  k_final_all<<<640, 256, 0, stream>>>(c);
  k_out<<<16, 64, 0, stream>>>(c);
}

// Round 4
// 1793.493 us; speedup vs baseline: 4.7137x; 1.1338x over previous
//
#include <hip/hip_runtime.h>
#include <float.h>
#include <math.h>

// Problem constants
#define BB 16
#define LL 400
#define TT 40
#define HH 256
#define EE 256
#define VOCAB 50000
#define NTILES 3128   // vocab tiles of 16 cols (782 groups of 4), 3128*16 = 50048 >= 50000
#define NPW NTILES    // pairs width

typedef __attribute__((ext_vector_type(8))) short bf16x8;
typedef __attribute__((ext_vector_type(4))) float f32x4;
typedef __attribute__((ext_vector_type(8))) unsigned short ushort8;

struct Ctx {
  // inputs
  const float *enc_states, *enc_h, *enc_c, *embed;
  const float *Wih, *Whh, *bih, *bhh;
  const float *Wh_w, *Wh_b, *Ws_w, *Ws_b;
  const float *wc_w, *wc_b, *v_w, *v_b;
  const float *wh_w, *wh_b, *ws_w, *ws_b, *wx_w, *wx_b;
  const float *V_w, *V_b;
  const int *dec_input, *targets, *article_inds;
  const unsigned char *enc_mask;
  // workspace
  float *Gx;        // [T,B,1024]
  float *hs;        // [T,B,256]
  float *dec_proj;  // [T,B,512]
  float *enc_proj;  // [B,L,512]
  float *WihT, *WsT, *WhT;
  float *coverage;  // [B,L]
  float *scores;    // [B,L]
  unsigned short *hcbA; // [T][96][16][8] bf16 A-fragments of concat(h,ctx), all steps
  float *pairs_m, *pairs_s;  // [640][NPW]
  float *px, *hws;  // [T*B]
  float *pgenA, *attnA, *logitA, *lmA; // [640]
  int *gidxA;       // [640]
  float *covl_sum;  // [16]
  unsigned short *hbuf_hi, *hbuf_lo;  // [2][4096] LSTM h exchange
  unsigned *bar;
  unsigned short *VF;  // [NTILES][24][4][16][8] bf16 V_w in B-frag order (optional)
  int use_bf16;
  float *out;       // [B]
};

__device__ __forceinline__ float sigf(float x) { return 1.f / (1.f + expf(-x)); }

__device__ __forceinline__ unsigned short f2bf(float x) {
  unsigned u = __builtin_bit_cast(unsigned, x);
  u = (u + 0x7FFFu + ((u >> 16) & 1u)) >> 16;
  return (unsigned short)u;
}
__device__ __forceinline__ float bf2f(unsigned short h) {
  unsigned u = ((unsigned)h) << 16;
  return __builtin_bit_cast(float, u);
}

// ---------------- init ----------------
__global__ void k_init(Ctx c) {
  int i = blockIdx.x * 256 + threadIdx.x;
  if (i < BB * LL) c.coverage[i] = 0.f;
  if (i < BB) c.covl_sum[i] = 0.f;
  if (i == 0) *c.bar = 0u;
}

// ---------------- V_w fp32 -> bf16 in MFMA B-frag order ----------------
// VF idx8(nt,kc,q,n) = nt*1536 + kc*64 + q*16 + n ; element j -> V_w[nt*16+n][kc*32+q*8+j]
__global__ void __launch_bounds__(256) k_cvtF(const float* __restrict__ V, unsigned short* __restrict__ VF) {
  __shared__ unsigned short tile[16][800];  // 16 rows x 768 (+pad)
  int nt = blockIdx.x;          // 0..NTILES-1
  int tid = threadIdx.x;        // 256
  for (int u = tid; u < 3072; u += 256) {
    int rr = u / 192, cc = u % 192;
    int v = nt * 16 + rr;
    float4 x = {0.f, 0.f, 0.f, 0.f};
    if (v < VOCAB) x = ((const float4*)(V + (size_t)v * 768))[cc];
    unsigned short* d = &tile[rr][cc * 4];
    d[0] = f2bf(x.x); d[1] = f2bf(x.y); d[2] = f2bf(x.z); d[3] = f2bf(x.w);
  }
  __syncthreads();
  ushort8* dst = (ushort8*)(VF + (size_t)nt * 12288);
  for (int u = tid; u < 1536; u += 256) {
    int n = u & 15, kq = u >> 4;     // kq = kc*4+q -> elem offset kq*8 = kc*32+q*8
    const unsigned short* s = &tile[n][kq * 8];
    ushort8 o;
#pragma unroll
    for (int j = 0; j < 8; ++j) o[j] = s[j];
    dst[u] = o;
  }
}

// ---------------- tiled transpose: in[R][C] -> out[C][R] ----------------
__global__ void k_transpose(const float* __restrict__ in, float* __restrict__ out, int R, int C) {
  __shared__ float tile[32][33];
  int bx = blockIdx.x * 32, by = blockIdx.y * 32;
  int tx = threadIdx.x, ty = threadIdx.y;
  for (int i = ty; i < 32; i += 8) tile[i][tx] = in[(by + i) * C + bx + tx];
  __syncthreads();
  for (int i = ty; i < 32; i += 8) out[(bx + i) * R + by + tx] = tile[tx][i];
}

// ---------------- Gx = embed[dec_input] @ Wih^T + bih + bhh ; px = e.wx ----------------
__global__ void k_gx(Ctx c) {
  int tb = blockIdx.x;
  int t = tb >> 4, b = tb & 15;
  int tid = threadIdx.x;          // 256
  __shared__ float x[EE];
  __shared__ float red[256];
  int tok = c.dec_input[b * TT + t];
  x[tid] = c.embed[(size_t)tok * EE + tid];
  __syncthreads();
  const float4* WT4 = (const float4*)c.WihT;
  float4 acc = ((const float4*)c.bih)[tid];
  float4 b2 = ((const float4*)c.bhh)[tid];
  acc.x += b2.x; acc.y += b2.y; acc.z += b2.z; acc.w += b2.w;
#pragma unroll 4
  for (int k = 0; k < EE; ++k) {
    float xv = x[k];
    float4 w = WT4[k * 256 + tid];
    acc.x += xv * w.x; acc.y += xv * w.y; acc.z += xv * w.z; acc.w += xv * w.w;
  }
  ((float4*)c.Gx)[tb * 256 + tid] = acc;
  red[tid] = x[tid] * c.wx_w[tid];
  __syncthreads();
  for (int s = 128; s > 0; s >>= 1) { if (tid < s) red[tid] += red[tid + s]; __syncthreads(); }
  if (tid == 0) c.px[tb] = red[0];
}

// ---------------- persistent MFMA LSTM: 16 WGs, Whh split-bf16 in VGPRs ----------------
__global__ void __launch_bounds__(256) k_lstm(Ctx c) {
  __shared__ unsigned short hAhi[4096], hAlo[4096];
  __shared__ float gs[4][16][16];
  int w = blockIdx.x, tid = threadIdx.x;
  int g = tid >> 6, lane = tid & 63;
  int n = lane & 15, q = lane >> 4;
  bf16x8 Bhi[8], Blo[8];
  {
    const float* wr = c.Whh + (size_t)(g * 256 + w * 16 + n) * 256;
#pragma unroll
    for (int kc = 0; kc < 8; ++kc) {
      const float* p8 = wr + kc * 32 + q * 8;
#pragma unroll
      for (int j = 0; j < 8; ++j) {
        float x = p8[j];
        unsigned short hi = f2bf(x);
        unsigned short lo = f2bf(x - bf2f(hi));
        Bhi[kc][j] = (short)hi; Blo[kc][j] = (short)lo;
      }
    }
  }
  for (int idx = tid; idx < 4096; idx += 256) {
    int b = idx >> 8, k = idx & 255;
    float x = c.enc_h[idx];
    unsigned short hi = f2bf(x);
    unsigned short lo = f2bf(x - bf2f(hi));
    int pos = (((k >> 5) * 4 + ((k >> 3) & 3)) * 16 + b) * 8 + (k & 7);
    hAhi[pos] = hi; hAlo[pos] = lo;
  }
  int bu = tid >> 4, ju = tid & 15;
  float creg = c.enc_c[bu * 256 + w * 16 + ju];
  __syncthreads();
  const bf16x8* Ahi = (const bf16x8*)hAhi;
  const bf16x8* Alo = (const bf16x8*)hAlo;
  int col = g * 256 + w * 16 + n;
  for (int t = 0; t < TT; ++t) {
    const float* gxp = c.Gx + (size_t)(t * 16) * 1024 + col;
    f32x4 acc;
    acc[0] = gxp[(q * 4 + 0) * 1024]; acc[1] = gxp[(q * 4 + 1) * 1024];
    acc[2] = gxp[(q * 4 + 2) * 1024]; acc[3] = gxp[(q * 4 + 3) * 1024];
#pragma unroll
    for (int kc = 0; kc < 8; ++kc) {
      bf16x8 ah = Ahi[(kc * 4 + q) * 16 + n];
      bf16x8 al = Alo[(kc * 4 + q) * 16 + n];
      acc = __builtin_amdgcn_mfma_f32_16x16x32_bf16(ah, Bhi[kc], acc, 0, 0, 0);
      acc = __builtin_amdgcn_mfma_f32_16x16x32_bf16(al, Bhi[kc], acc, 0, 0, 0);
      acc = __builtin_amdgcn_mfma_f32_16x16x32_bf16(ah, Blo[kc], acc, 0, 0, 0);
    }
#pragma unroll
    for (int r = 0; r < 4; ++r) gs[g][q * 4 + r][n] = acc[r];
    __syncthreads();
    {
      float ig = gs[0][bu][ju], fg = gs[1][bu][ju], gg = gs[2][bu][ju], og = gs[3][bu][ju];
      creg = sigf(fg) * creg + sigf(ig) * tanhf(gg);
      float hv = sigf(og) * tanhf(creg);
      int j = w * 16 + ju;
      c.hs[(t * 16 + bu) * 256 + j] = hv;
      unsigned short hi = f2bf(hv);
      unsigned short lo = f2bf(hv - bf2f(hi));
      int pos = (((j >> 5) * 4 + ((j >> 3) & 3)) * 16 + bu) * 8 + (j & 7);
      int par = (t + 1) & 1;
      c.hbuf_hi[par * 4096 + pos] = hi;
      c.hbuf_lo[par * 4096 + pos] = lo;
    }
    __threadfence();
    __syncthreads();
    if (tid == 0) {
      __hip_atomic_fetch_add(c.bar, 1u, __ATOMIC_ACQ_REL, __HIP_MEMORY_SCOPE_AGENT);
      while (__hip_atomic_load(c.bar, __ATOMIC_ACQUIRE, __HIP_MEMORY_SCOPE_AGENT) < (unsigned)(16 * (t + 1)))
        __builtin_amdgcn_s_sleep(2);
      __threadfence();
    }
    __syncthreads();
    if (t < TT - 1) {
      int par = (t + 1) & 1;
      for (int idx = tid; idx < 4096; idx += 256) {
        hAhi[idx] = c.hbuf_hi[par * 4096 + idx];
        hAlo[idx] = c.hbuf_lo[par * 4096 + idx];
      }
      __syncthreads();
    }
  }
}

// ---------------- dec_proj = hs @ Ws^T + Ws_b ; hws = h.ws ----------------
__global__ void k_decproj(Ctx c) {
  int tb = blockIdx.x, tid = threadIdx.x;  // block 512
  __shared__ float h[256];
  __shared__ float red[256];
  if (tid < 256) h[tid] = c.hs[tb * 256 + tid];
  __syncthreads();
  float acc = c.Ws_b[tid];
#pragma unroll 4
  for (int k = 0; k < 256; ++k) acc += h[k] * c.WsT[k * 512 + tid];
  c.dec_proj[tb * 512 + tid] = acc;
  if (tid < 256) red[tid] = h[tid] * c.ws_w[tid];
  __syncthreads();
  for (int s = 128; s > 0; s >>= 1) { if (tid < 256 && tid < s) red[tid] += red[tid + s]; __syncthreads(); }
  if (tid == 0) c.hws[tb] = red[0];
}

// ---------------- enc_proj = enc_states @ Wh^T + Wh_b ----------------
__global__ void k_encproj(Ctx c) {
  int b = blockIdx.x / 100, lt = (blockIdx.x % 100) * 4, tid = threadIdx.x; // block 512
  __shared__ float es[4][512];
  for (int i = 0; i < 4; ++i) es[i][tid] = c.enc_states[(size_t)(b * LL + lt + i) * 512 + tid];
  __syncthreads();
  float bias = c.Wh_b[tid];
  float a0 = bias, a1 = bias, a2 = bias, a3 = bias;
#pragma unroll 4
  for (int k = 0; k < 512; ++k) {
    float w = c.WhT[k * 512 + tid];
    a0 += es[0][k] * w; a1 += es[1][k] * w; a2 += es[2][k] * w; a3 += es[3][k] * w;
  }
  c.enc_proj[(size_t)(b * LL + lt + 0) * 512 + tid] = a0;
  c.enc_proj[(size_t)(b * LL + lt + 1) * 512 + tid] = a1;
  c.enc_proj[(size_t)(b * LL + lt + 2) * 512 + tid] = a2;
  c.enc_proj[(size_t)(b * LL + lt + 3) * 512 + tid] = a3;
}

// ---------------- S1: attention scores ----------------
__global__ void k_scores(Ctx c, int t) {
  int wv = blockIdx.x * 4 + (threadIdx.x >> 6);
  int lane = threadIdx.x & 63;
  int b = wv / 400, l = wv % 400;
  float cov = c.coverage[b * LL + l];
  const float* ep = c.enc_proj + (size_t)(b * LL + l) * 512;
  const float* dp = c.dec_proj + (size_t)(t * 16 + b) * 512;
  float acc = 0.f;
#pragma unroll
  for (int i = 0; i < 8; ++i) {
    int j = lane + 64 * i;
    float f = ep[j] + dp[j] + cov * c.wc_w[j] + c.wc_b[j];
    acc += tanhf(f) * c.v_w[j];
  }
  for (int off = 1; off < 64; off <<= 1) acc += __shfl_xor(acc, off, 64);
  if (lane == 0) {
    float s = acc + c.v_b[0];
    if (c.enc_mask[b * LL + l]) s = -1e30f;
    c.scores[b * LL + l] = s;
  }
}

// ---------------- S2: softmax + coverage + context + pgen + hcbA archive ----------------
__global__ void __launch_bounds__(1024) k_step(Ctx c, int t) {
  int b = blockIdx.x, tid = threadIdx.x; // block 1024
  __shared__ float red[1024];
  __shared__ float attn_s[400];
  float sc = (tid < 400) ? c.scores[b * LL + tid] : -FLT_MAX;
  red[tid] = sc; __syncthreads();
  for (int s = 512; s > 0; s >>= 1) { if (tid < s) red[tid] = fmaxf(red[tid], red[tid + s]); __syncthreads(); }
  float M2 = red[0]; __syncthreads();
  float ex = (tid < 400) ? __expf(sc - M2) : 0.f;
  red[tid] = ex; __syncthreads();
  for (int s = 512; s > 0; s >>= 1) { if (tid < s) red[tid] += red[tid + s]; __syncthreads(); }
  float S = red[0]; __syncthreads();
  float a = ex / S;
  if (tid < 400) attn_s[tid] = a;
  int tgt_t = c.targets[b * TT + t];
  int gidx = (tgt_t != 0) ? tgt_t - 1 : 0;
  if (tid == 0) c.gidxA[t * 16 + b] = gidx;
  float cvp = 0.f, mct = 0.f;
  if (tid < 400) {
    float nc = c.coverage[b * LL + tid] + a;
    c.coverage[b * LL + tid] = nc;
    cvp = fminf(nc, a);
    int idx = c.enc_mask[b * LL + tid] ? 0 : (c.article_inds[b * LL + tid] - 1);
    mct = (idx == gidx) ? a : 0.f;
  }
  red[tid] = cvp; __syncthreads();
  for (int s = 512; s > 0; s >>= 1) { if (tid < s) red[tid] += red[tid + s]; __syncthreads(); }
  if (tid == 0) c.covl_sum[b] += red[0];
  __syncthreads();
  red[tid] = mct; __syncthreads();
  for (int s = 512; s > 0; s >>= 1) { if (tid < s) red[tid] += red[tid + s]; __syncthreads(); }
  if (tid == 0) c.attnA[t * 16 + b] = red[0];
  __syncthreads();
  int j = tid & 511, half = tid >> 9;
  float part = 0.f;
  {
    const float* esb = c.enc_states + (size_t)b * LL * 512 + j;
    int l0 = half * 200;
#pragma unroll 4
    for (int l = l0; l < l0 + 200; ++l) part += attn_s[l] * esb[(size_t)l * 512];
  }
  red[tid] = part; __syncthreads();
  float ctx = 0.f;
  unsigned short* hct = c.hcbA + (size_t)t * 12288;
  if (tid < 512) {
    ctx = red[tid] + red[tid + 512];
    int jj = 256 + j;
    hct[(jj >> 3) * 128 + b * 8 + (jj & 7)] = f2bf(ctx);
    if (tid < 256) {
      float hv = c.hs[(t * 16 + b) * 256 + tid];
      hct[(tid >> 3) * 128 + b * 8 + (tid & 7)] = f2bf(hv);
    }
  }
  __syncthreads();
  red[tid] = (tid < 512) ? ctx * c.wh_w[j] : 0.f;
  __syncthreads();
  for (int s = 512; s > 0; s >>= 1) { if (tid < s) red[tid] += red[tid + s]; __syncthreads(); }
  if (tid == 0) {
    float pg = red[0] + c.wh_b[0] + c.hws[t * 16 + b] + c.ws_b[0] + c.px[t * 16 + b] + c.wx_b[0];
    c.pgenA[t * 16 + b] = sigf(pg);
  }
}

// ---------------- one-shot vocab GEMM, barrier-free, LDS-free ----------------
// Block = 4 waves: wave wv -> vocab tile nt = (blockIdx>>2)*4 + wv (16 cols),
// t-group tg = blockIdx&3 (10 t-tiles). D = 10 f32x4 per lane.
// Lane: n = lane&15 (col within tile AND batch row for A), q = lane>>4 (K-quad).
__global__ void __launch_bounds__(256, 4) k_vocab_all(Ctx c) {
  int tid = threadIdx.x;
  int wv = tid >> 6, lane = tid & 63;
  int n = lane & 15, q = lane >> 4;
  int cg = blockIdx.x >> 2, tg = blockIdx.x & 3;
  int nt = cg * 4 + wv;
  int col = nt * 16 + n;
  bool vld = col < VOCAB;
  int colc = vld ? col : VOCAB - 1;
  float vb = c.V_b[colc];
  int t0 = tg * 10;
  f32x4 D[10];
#pragma unroll
  for (int i = 0; i < 10; ++i) D[i] = (f32x4){0.f, 0.f, 0.f, 0.f};
  const bf16x8* A8 = (const bf16x8*)c.hcbA;
  size_t abase = ((size_t)t0 * 96) * 16 + q * 16 + n;   // + i*1536 + kc*64
  if (c.use_bf16) {
    const bf16x8* BF = (const bf16x8*)c.VF;
    size_t bbase = (size_t)nt * 1536 + q * 16 + n;      // + kc*64
    for (int kc = 0; kc < 24; ++kc) {
      bf16x8 B = BF[bbase + kc * 64];
#pragma unroll
      for (int i = 0; i < 10; ++i) {
        bf16x8 a = A8[abase + (size_t)i * 1536 + kc * 64];
        D[i] = __builtin_amdgcn_mfma_f32_16x16x32_bf16(a, B, D[i], 0, 0, 0);
      }
    }
  } else {
    for (int kc = 0; kc < 24; ++kc) {
      const float4* vr = (const float4*)(c.V_w + (size_t)colc * 768 + kc * 32 + q * 8);
      float4 b0 = vr[0], b1 = vr[1];
      bf16x8 B;
      B[0] = (short)f2bf(b0.x); B[1] = (short)f2bf(b0.y); B[2] = (short)f2bf(b0.z); B[3] = (short)f2bf(b0.w);
      B[4] = (short)f2bf(b1.x); B[5] = (short)f2bf(b1.y); B[6] = (short)f2bf(b1.z); B[7] = (short)f2bf(b1.w);
#pragma unroll
      for (int i = 0; i < 10; ++i) {
        bf16x8 a = A8[abase + (size_t)i * 1536 + kc * 64];
        D[i] = __builtin_amdgcn_mfma_f32_16x16x32_bf16(a, B, D[i], 0, 0, 0);
      }
    }
  }
  // epilogue: bias + target logit + per-(t,b) online-softmax over this wave's 16 cols
#pragma unroll
  for (int i = 0; i < 10; ++i) {
    int t = t0 + i;
#pragma unroll
    for (int r = 0; r < 4; ++r) {
      int b = q * 4 + r;
      int rw = t * 16 + b;
      float lg = D[i][r] + vb;
      if (vld && col == c.gidxA[rw]) c.logitA[rw] = lg;
      float m_ = vld ? lg : -FLT_MAX;
      float s_ = vld ? 1.f : 0.f;
#pragma unroll
      for (int off = 1; off < 16; off <<= 1) {
        float om = __shfl_xor(m_, off, 16);
        float os = __shfl_xor(s_, off, 16);
        float M = fmaxf(m_, om);
        s_ = s_ * __expf(m_ - M) + os * __expf(om - M);
        m_ = M;
      }
      if (n == 0) {
        c.pairs_m[(size_t)rw * NPW + nt] = m_;
        c.pairs_s[(size_t)rw * NPW + nt] = s_;
      }
    }
  }
}

// ---------------- per-(t,b) loss from pairs ----------------
__global__ void k_final_all(Ctx c) {
  int row = blockIdx.x;  // t*16 + b
  int tid = threadIdx.x; // 256
  __shared__ float red[256];
  float m = -FLT_MAX;
  for (int i = tid; i < NPW; i += 256) m = fmaxf(m, c.pairs_m[(size_t)row * NPW + i]);
  red[tid] = m; __syncthreads();
  for (int s = 128; s > 0; s >>= 1) { if (tid < s) red[tid] = fmaxf(red[tid], red[tid + s]); __syncthreads(); }
  float M = red[0]; __syncthreads();
  float z = 0.f;
  for (int i = tid; i < NPW; i += 256)
    z += c.pairs_s[(size_t)row * NPW + i] * __expf(c.pairs_m[(size_t)row * NPW + i] - M);
  red[tid] = z; __syncthreads();
  for (int s = 128; s > 0; s >>= 1) { if (tid < s) red[tid] += red[tid + s]; __syncthreads(); }
  if (tid == 0) {
    int t = row >> 4, b = row & 15;
    int tgt = c.targets[b * TT + t];
    float lm = 0.f;
    if (tgt != 0) {
      float p = __expf(c.logitA[row] - M) / red[0];
      float pg = c.pgenA[row];
      lm = -logf(pg * p + (1.f - pg) * c.attnA[row]);
    }
    c.lmA[row] = lm;
  }
}

// ---------------- output ----------------
__global__ void k_out(Ctx c) {
  int b = blockIdx.x, tid = threadIdx.x; // 64 threads
  float lm = (tid < TT) ? c.lmA[tid * 16 + b] : 0.f;
  float dl = (tid < TT && c.dec_input[b * TT + tid] > 0) ? 1.f : 0.f;
  for (int off = 1; off < 64; off <<= 1) {
    lm += __shfl_xor(lm, off, 64);
    dl += __shfl_xor(dl, off, 64);
  }
  if (tid == 0) c.out[b] = lm / dl + c.covl_sum[b] / dl;
}

extern "C" void kernel_launch(void* const* d_in, const int* in_sizes, int n_in,
                              void* d_out, int out_size, void* d_ws, size_t ws_size,
                              hipStream_t stream) {
  Ctx c;
  c.enc_states = (const float*)d_in[0];
  c.enc_h      = (const float*)d_in[1];
  c.enc_c      = (const float*)d_in[2];
  c.embed      = (const float*)d_in[3];
  c.Wih        = (const float*)d_in[4];
  c.Whh        = (const float*)d_in[5];
  c.bih        = (const float*)d_in[6];
  c.bhh        = (const float*)d_in[7];
  c.Wh_w       = (const float*)d_in[8];
  c.Wh_b       = (const float*)d_in[9];
  c.Ws_w       = (const float*)d_in[10];
  c.Ws_b       = (const float*)d_in[11];
  c.wc_w       = (const float*)d_in[12];
  c.wc_b       = (const float*)d_in[13];
  c.v_w        = (const float*)d_in[14];
  c.v_b        = (const float*)d_in[15];
  c.wh_w       = (const float*)d_in[16];
  c.wh_b       = (const float*)d_in[17];
  c.ws_w       = (const float*)d_in[18];
  c.ws_b       = (const float*)d_in[19];
  c.wx_w       = (const float*)d_in[20];
  c.wx_b       = (const float*)d_in[21];
  c.V_w        = (const float*)d_in[22];
  c.V_b        = (const float*)d_in[23];
  c.dec_input  = (const int*)d_in[24];
  c.targets    = (const int*)d_in[25];
  c.article_inds = (const int*)d_in[26];
  c.enc_mask   = (const unsigned char*)d_in[27];

  float* p = (float*)d_ws;
  c.Gx = p;        p += TT * BB * 1024;
  c.hs = p;        p += TT * BB * 256;
  c.dec_proj = p;  p += TT * BB * 512;
  c.enc_proj = p;  p += (size_t)BB * LL * 512;
  c.WihT = p;      p += 1024 * 256;
  c.WsT = p;       p += 512 * 256;
  c.WhT = p;       p += 512 * 512;
  c.coverage = p;  p += BB * LL;
  c.scores = p;    p += BB * LL;
  c.hcbA = (unsigned short*)p; p += TT * BB * 768 / 2;
  c.pairs_m = p;   p += (size_t)640 * NPW;
  c.pairs_s = p;   p += (size_t)640 * NPW;
  c.px = p;        p += TT * BB;
  c.hws = p;       p += TT * BB;
  c.pgenA = p;     p += 640;
  c.attnA = p;     p += 640;
  c.logitA = p;    p += 640;
  c.lmA = p;       p += 640;
  c.gidxA = (int*)p; p += 640;
  c.covl_sum = p;  p += 16;
  c.hbuf_hi = (unsigned short*)p; p += 2 * 4096 / 2;
  c.hbuf_lo = (unsigned short*)p; p += 2 * 4096 / 2;
  c.bar = (unsigned*)p; p += 16;
  c.VF = (unsigned short*)p;
  size_t used_bytes = (size_t)((char*)p - (char*)d_ws);
  size_t vf_bytes = (size_t)NTILES * 12288 * 2;
  c.use_bf16 = (used_bytes + vf_bytes <= ws_size) ? 1 : 0;
  c.out = (float*)d_out;

  k_init<<<26, 256, 0, stream>>>(c);
  if (c.use_bf16) k_cvtF<<<NTILES, 256, 0, stream>>>(c.V_w, c.VF);
  k_transpose<<<dim3(8, 32), dim3(32, 8), 0, stream>>>(c.Wih, c.WihT, 1024, 256);
  k_transpose<<<dim3(8, 16), dim3(32, 8), 0, stream>>>(c.Ws_w, c.WsT, 512, 256);
  k_transpose<<<dim3(16, 16), dim3(32, 8), 0, stream>>>(c.Wh_w, c.WhT, 512, 512);
  k_gx<<<TT * BB, 256, 0, stream>>>(c);
  k_encproj<<<16 * 100, 512, 0, stream>>>(c);
  k_lstm<<<16, 256, 0, stream>>>(c);
  k_decproj<<<TT * BB, 512, 0, stream>>>(c);
  for (int t = 0; t < TT; ++t) {
    k_scores<<<1600, 256, 0, stream>>>(c, t);
    k_step<<<16, 1024, 0, stream>>>(c, t);
  }
  k_vocab_all<<<782 * 4, 256, 0, stream>>>(c);
  k_final_all<<<640, 256, 0, stream>>>(c);
  k_out<<<16, 64, 0, stream>>>(c);
}